// Round 1
// baseline (749.036 us; speedup 1.0000x reference)
//
#include <hip/hip_runtime.h>
#include <math.h>

#define Bb 8
#define Nn 96
#define Dd 256
#define Hh 8
#define BN (Bb*Nn)
#define PI_OVER_CUTOFF 0.62831853071795864769f  /* pi/5 */

__device__ __forceinline__ float silu_f(float x){ return x / (1.0f + expf(-x)); }

// ---------------- Kernel 1: q,k,v = x @ W{q,k,v} + b ----------------
// grid = BN/4 blocks, 256 threads. Each block computes 4 rows of all three.
__global__ __launch_bounds__(256) void qkv_kernel(
    const float* __restrict__ x,
    const float* __restrict__ Wq, const float* __restrict__ bq,
    const float* __restrict__ Wk, const float* __restrict__ bk,
    const float* __restrict__ Wv, const float* __restrict__ bv,
    float* __restrict__ qo, float* __restrict__ ko, float* __restrict__ vo)
{
    __shared__ float xs[4][Dd];
    const int tid = threadIdx.x;
    const int r0  = blockIdx.x * 4;
    #pragma unroll
    for (int i = 0; i < 4; ++i) xs[i][tid] = x[(size_t)(r0 + i) * Dd + tid];
    __syncthreads();

    float aq[4], ak[4], av[4];
    const float bqv = bq[tid], bkv = bk[tid], bvv = bv[tid];
    #pragma unroll
    for (int i = 0; i < 4; ++i) { aq[i] = bqv; ak[i] = bkv; av[i] = bvv; }

    for (int kk = 0; kk < Dd; ++kk) {
        const float wq = Wq[(size_t)kk * Dd + tid];
        const float wk = Wk[(size_t)kk * Dd + tid];
        const float wv = Wv[(size_t)kk * Dd + tid];
        #pragma unroll
        for (int i = 0; i < 4; ++i) {
            const float xv = xs[i][kk];
            aq[i] = fmaf(xv, wq, aq[i]);
            ak[i] = fmaf(xv, wk, ak[i]);
            av[i] = fmaf(xv, wv, av[i]);
        }
    }
    #pragma unroll
    for (int i = 0; i < 4; ++i) {
        qo[(size_t)(r0 + i) * Dd + tid] = aq[i];
        ko[(size_t)(r0 + i) * Dd + tid] = ak[i];
        vo[(size_t)(r0 + i) * Dd + tid] = av[i];
    }
}

// ---------------- Kernel 2: fused dk-GEMM + attention + m-reductions ----------------
// One block per (b,n). Computes, for all m:
//   dk = silu(edge[b,n,m,:] @ Wdk + bdk)
//   aw[h] = sum_d q[b,n,h,d]*k[b,m,h,d]*dk[h,d]   (masked -> 0)
//   p[h]  = silu(aw[h]) * scale(dist)             (scale=0 if masked or dist>=5)
//   apn[m,d] = p[h(d)] * v[b,m,d]
// and accumulates attn[d] = sum_m apn,  t[c,d] = sum_m vec[m,c]*apn,
// svec[c] = sum_{m unmasked} vec[m,c].
__global__ __launch_bounds__(256) void attn_kernel(
    const float* __restrict__ q, const float* __restrict__ kmat, const float* __restrict__ vmat,
    const float* __restrict__ edge, const float* __restrict__ Wdk, const float* __restrict__ bdk,
    const int* __restrict__ mask, const float* __restrict__ dist, const float* __restrict__ vec,
    float* __restrict__ attn_out, float* __restrict__ t_out, float* __restrict__ sv_out)
{
    const int bn  = blockIdx.x;
    const int b   = bn / Nn;
    const int tid = threadIdx.x;

    __shared__ float qs[Dd];
    __shared__ float es[32][Dd];
    __shared__ float scl[Nn];
    __shared__ float vcs[Nn][3];
    __shared__ int   mks[Nn];

    qs[tid] = q[(size_t)bn * Dd + tid];
    if (tid < Nn) {
        const int   mm = mask[(size_t)bn * Nn + tid];
        const float di = dist[(size_t)bn * Nn + tid];
        const float s  = (di < 5.0f) ? 0.5f * (cosf(di * PI_OVER_CUTOFF) + 1.0f) : 0.0f;
        scl[tid] = mm ? 0.0f : s;
        mks[tid] = mm;
    }
    for (int j = tid; j < Nn * 3; j += 256)
        (&vcs[0][0])[j] = vec[(size_t)bn * Nn * 3 + j];

    float attn_acc = 0.0f, t0 = 0.0f, t1 = 0.0f, t2 = 0.0f;
    const float bd = bdk[tid];
    const float* eb = edge + (size_t)bn * Nn * Dd;
    __syncthreads();

    for (int mt = 0; mt < 3; ++mt) {
        if (mt) __syncthreads();
        // stage 32 contiguous edge rows (32*256 floats) into LDS
        const float4* e4  = (const float4*)(eb + (size_t)mt * 32 * Dd);
        float4*       es4 = (float4*)&es[0][0];
        #pragma unroll
        for (int j = 0; j < 8; ++j) es4[j * 256 + tid] = e4[j * 256 + tid];
        __syncthreads();

        float acc[32];
        #pragma unroll
        for (int i = 0; i < 32; ++i) acc[i] = bd;

        for (int k4 = 0; k4 < 64; ++k4) {
            const float w0 = Wdk[(size_t)(k4 * 4 + 0) * Dd + tid];
            const float w1 = Wdk[(size_t)(k4 * 4 + 1) * Dd + tid];
            const float w2 = Wdk[(size_t)(k4 * 4 + 2) * Dd + tid];
            const float w3 = Wdk[(size_t)(k4 * 4 + 3) * Dd + tid];
            #pragma unroll
            for (int i = 0; i < 32; ++i) {
                const float4 e = *(const float4*)&es[i][k4 * 4];
                acc[i] = fmaf(e.x, w0, fmaf(e.y, w1, fmaf(e.z, w2, fmaf(e.w, w3, acc[i]))));
            }
        }

        for (int i = 0; i < 32; ++i) {
            const int m = mt * 32 + i;
            const float dkv = silu_f(acc[i]);
            float prod = qs[tid] * kmat[(size_t)(b * Nn + m) * Dd + tid] * dkv;
            // reduce over the 32 lanes sharing one head (d = tid, h = tid>>5)
            #pragma unroll
            for (int off = 16; off >= 1; off >>= 1)
                prod += __shfl_xor(prod, off, 32);
            const float p  = silu_f(prod) * scl[m];   // scl==0 covers mask & cutoff
            const float pv = p * vmat[(size_t)(b * Nn + m) * Dd + tid];
            attn_acc += pv;
            t0 = fmaf(vcs[m][0], pv, t0);
            t1 = fmaf(vcs[m][1], pv, t1);
            t2 = fmaf(vcs[m][2], pv, t2);
        }
    }

    attn_out[(size_t)bn * Dd + tid] = attn_acc;
    t_out[((size_t)bn * 3 + 0) * Dd + tid] = t0;
    t_out[((size_t)bn * 3 + 1) * Dd + tid] = t1;
    t_out[((size_t)bn * 3 + 2) * Dd + tid] = t2;
    if (tid < 3) {
        float s = 0.0f;
        for (int m = 0; m < Nn; ++m) if (!mks[m]) s += vcs[m][tid];
        sv_out[(size_t)bn * 3 + tid] = s;
    }
}

// ---------------- Kernel 3: du = t@Wdu + svec*bdu ; w = du@Wdih -> ws,wt ----------------
// grid = BN/4 blocks (4 bn-rows x 3 c = 12 rows each), 256 threads.
__global__ __launch_bounds__(256) void du_kernel(
    const float* __restrict__ t_in, const float* __restrict__ sv_in,
    const float* __restrict__ Wdu, const float* __restrict__ bdu,
    const float* __restrict__ Wdih,
    float* __restrict__ wsv, float* __restrict__ wtv)
{
    const int r0  = blockIdx.x * 4;   // first bn row
    const int tid = threadIdx.x;
    __shared__ float ts[12][Dd];
    __shared__ float dus[12][Dd];

    #pragma unroll
    for (int j = 0; j < 12; ++j)
        ts[j][tid] = t_in[((size_t)r0 * 3 + j) * Dd + tid];
    __syncthreads();

    float du[12];
    const float bd = bdu[tid];
    #pragma unroll
    for (int j = 0; j < 12; ++j) du[j] = sv_in[(size_t)r0 * 3 + j] * bd;

    for (int k4 = 0; k4 < 64; ++k4) {
        const float w0 = Wdu[(size_t)(k4 * 4 + 0) * Dd + tid];
        const float w1 = Wdu[(size_t)(k4 * 4 + 1) * Dd + tid];
        const float w2 = Wdu[(size_t)(k4 * 4 + 2) * Dd + tid];
        const float w3 = Wdu[(size_t)(k4 * 4 + 3) * Dd + tid];
        #pragma unroll
        for (int j = 0; j < 12; ++j) {
            const float4 e = *(const float4*)&ts[j][k4 * 4];
            du[j] = fmaf(e.x, w0, fmaf(e.y, w1, fmaf(e.z, w2, fmaf(e.w, w3, du[j]))));
        }
    }
    #pragma unroll
    for (int j = 0; j < 12; ++j) dus[j][tid] = du[j];
    __syncthreads();

    float as[12], at[12];
    #pragma unroll
    for (int j = 0; j < 12; ++j) { as[j] = 0.0f; at[j] = 0.0f; }

    for (int k4 = 0; k4 < 64; ++k4) {
        const float s0 = Wdih[(size_t)(k4 * 4 + 0) * 512 + tid];
        const float s1 = Wdih[(size_t)(k4 * 4 + 1) * 512 + tid];
        const float s2 = Wdih[(size_t)(k4 * 4 + 2) * 512 + tid];
        const float s3 = Wdih[(size_t)(k4 * 4 + 3) * 512 + tid];
        const float u0 = Wdih[(size_t)(k4 * 4 + 0) * 512 + 256 + tid];
        const float u1 = Wdih[(size_t)(k4 * 4 + 1) * 512 + 256 + tid];
        const float u2 = Wdih[(size_t)(k4 * 4 + 2) * 512 + 256 + tid];
        const float u3 = Wdih[(size_t)(k4 * 4 + 3) * 512 + 256 + tid];
        #pragma unroll
        for (int j = 0; j < 12; ++j) {
            const float4 e = *(const float4*)&dus[j][k4 * 4];
            as[j] = fmaf(e.x, s0, fmaf(e.y, s1, fmaf(e.z, s2, fmaf(e.w, s3, as[j]))));
            at[j] = fmaf(e.x, u0, fmaf(e.y, u1, fmaf(e.z, u2, fmaf(e.w, u3, at[j]))));
        }
    }
    #pragma unroll
    for (int j = 0; j < 12; ++j) {
        wsv[((size_t)r0 * 3 + j) * Dd + tid] = as[j];
        wtv[((size_t)r0 * 3 + j) * Dd + tid] = at[j];
    }
}

// ---------------- Kernel 4: ipe = silu(edge@Wea + bea) * sum_c ws[n,c]*wt[m,c] ----------------
__global__ __launch_bounds__(256) void ipe_kernel(
    const float* __restrict__ edge, const float* __restrict__ Wea, const float* __restrict__ bea,
    const float* __restrict__ wsv, const float* __restrict__ wtv,
    float* __restrict__ ipe)
{
    const int bn  = blockIdx.x;
    const int b   = bn / Nn;
    const int tid = threadIdx.x;
    __shared__ float es[32][Dd];
    __shared__ float wss[3][Dd];

    #pragma unroll
    for (int c = 0; c < 3; ++c)
        wss[c][tid] = wsv[((size_t)bn * 3 + c) * Dd + tid];
    const float be = bea[tid];
    const float* eb = edge + (size_t)bn * Nn * Dd;
    __syncthreads();

    for (int mt = 0; mt < 3; ++mt) {
        if (mt) __syncthreads();
        const float4* e4  = (const float4*)(eb + (size_t)mt * 32 * Dd);
        float4*       es4 = (float4*)&es[0][0];
        #pragma unroll
        for (int j = 0; j < 8; ++j) es4[j * 256 + tid] = e4[j * 256 + tid];
        __syncthreads();

        float acc[32];
        #pragma unroll
        for (int i = 0; i < 32; ++i) acc[i] = be;

        for (int k4 = 0; k4 < 64; ++k4) {
            const float w0 = Wea[(size_t)(k4 * 4 + 0) * Dd + tid];
            const float w1 = Wea[(size_t)(k4 * 4 + 1) * Dd + tid];
            const float w2 = Wea[(size_t)(k4 * 4 + 2) * Dd + tid];
            const float w3 = Wea[(size_t)(k4 * 4 + 3) * Dd + tid];
            #pragma unroll
            for (int i = 0; i < 32; ++i) {
                const float4 e = *(const float4*)&es[i][k4 * 4];
                acc[i] = fmaf(e.x, w0, fmaf(e.y, w1, fmaf(e.z, w2, fmaf(e.w, w3, acc[i]))));
            }
        }

        for (int i = 0; i < 32; ++i) {
            const int m = mt * 32 + i;
            const float ea = silu_f(acc[i]);
            const float* wtb = wtv + ((size_t)(b * Nn + m) * 3) * Dd;
            const float val = ea * (wss[0][tid] * wtb[tid] +
                                    wss[1][tid] * wtb[Dd + tid] +
                                    wss[2][tid] * wtb[2 * Dd + tid]);
            ipe[((size_t)bn * Nn + m) * Dd + tid] = val;
        }
    }
}

extern "C" void kernel_launch(void* const* d_in, const int* in_sizes, int n_in,
                              void* d_out, int out_size, void* d_ws, size_t ws_size,
                              hipStream_t stream)
{
    const float* x    = (const float*)d_in[0];
    const float* vec  = (const float*)d_in[1];
    const float* dist = (const float*)d_in[2];
    const float* edge = (const float*)d_in[3];
    const int*   mask = (const int*)d_in[4];
    const float* Wq   = (const float*)d_in[5];
    const float* bq   = (const float*)d_in[6];
    const float* Wk   = (const float*)d_in[7];
    const float* bk   = (const float*)d_in[8];
    const float* Wv   = (const float*)d_in[9];
    const float* bv   = (const float*)d_in[10];
    const float* Wdk  = (const float*)d_in[11];
    const float* bdk  = (const float*)d_in[12];
    const float* Wdu  = (const float*)d_in[13];
    const float* bdu  = (const float*)d_in[14];
    const float* Wdih = (const float*)d_in[15];
    const float* Wea  = (const float*)d_in[16];
    const float* bea  = (const float*)d_in[17];

    float* out_attn = (float*)d_out;
    float* out_ipe  = out_attn + (size_t)BN * Dd;

    float* ws  = (float*)d_ws;
    float* qb  = ws;
    float* kb  = qb  + (size_t)BN * Dd;
    float* vb  = kb  + (size_t)BN * Dd;
    float* tb  = vb  + (size_t)BN * Dd;
    float* svb = tb  + (size_t)BN * 3 * Dd;
    float* wsv = svb + (size_t)BN * 3;
    float* wtv = wsv + (size_t)BN * 3 * Dd;

    qkv_kernel<<<BN / 4, 256, 0, stream>>>(x, Wq, bq, Wk, bk, Wv, bv, qb, kb, vb);
    attn_kernel<<<BN, 256, 0, stream>>>(qb, kb, vb, edge, Wdk, bdk, mask, dist, vec,
                                        out_attn, tb, svb);
    du_kernel<<<BN / 4, 256, 0, stream>>>(tb, svb, Wdu, bdu, Wdih, wsv, wtv);
    ipe_kernel<<<BN, 256, 0, stream>>>(edge, Wea, bea, wsv, wtv, out_ipe);
}

// Round 2
// 409.703 us; speedup vs baseline: 1.8282x; 1.8282x over previous
//
#include <hip/hip_runtime.h>
#include <hip/hip_bf16.h>
#include <math.h>

#define Bb 8
#define Nn 96
#define Dd 256
#define BN (Bb*Nn)      /* 768 */
#define MT (BN*Nn)      /* 73728 edge rows */
#define PI_OVER_CUTOFF 0.62831853071795864769f  /* pi/5 */

typedef short short8 __attribute__((ext_vector_type(8)));
typedef float f32x4  __attribute__((ext_vector_type(4)));

__device__ __forceinline__ float silu_f(float x){ return x / (1.0f + expf(-x)); }

__device__ __forceinline__ short f2bf(float f){
    __hip_bfloat16 h = __float2bfloat16(f);
    return __builtin_bit_cast(short, h);
}
__device__ __forceinline__ float bf2f(unsigned short u){
    union { unsigned uu; float ff; } a; a.uu = ((unsigned)u) << 16; return a.ff;
}

// ---------------- Kernel 0: Wt = bf16(W^T) for Wdk and Wea ----------------
// grid 512 x 256 threads. o = sel*65536 + n*256 + k ; Wt[n][k] = W[k][n]
__global__ __launch_bounds__(256) void wt_kernel(
    const float* __restrict__ Wdk, const float* __restrict__ Wea,
    short* __restrict__ Wtdk, short* __restrict__ Wtea)
{
    const int o   = blockIdx.x * 256 + threadIdx.x;
    const int sel = o >> 16;
    const int r   = o & 65535;
    const int n   = r >> 8, k = r & 255;
    const float* src = sel ? Wea : Wdk;
    short*       dst = sel ? Wtea : Wtdk;
    dst[r] = f2bf(src[k * 256 + n]);
}

// ---------------- Kernel 1: q,k,v projections (unchanged) ----------------
__global__ __launch_bounds__(256) void qkv_kernel(
    const float* __restrict__ x,
    const float* __restrict__ Wq, const float* __restrict__ bq,
    const float* __restrict__ Wk, const float* __restrict__ bk,
    const float* __restrict__ Wv, const float* __restrict__ bv,
    float* __restrict__ qo, float* __restrict__ ko, float* __restrict__ vo)
{
    __shared__ float xs[4][Dd];
    const int tid = threadIdx.x;
    const int r0  = blockIdx.x * 4;
    #pragma unroll
    for (int i = 0; i < 4; ++i) xs[i][tid] = x[(size_t)(r0 + i) * Dd + tid];
    __syncthreads();

    float aq[4], ak[4], av[4];
    const float bqv = bq[tid], bkv = bk[tid], bvv = bv[tid];
    #pragma unroll
    for (int i = 0; i < 4; ++i) { aq[i] = bqv; ak[i] = bkv; av[i] = bvv; }

    for (int kk = 0; kk < Dd; ++kk) {
        const float wq = Wq[(size_t)kk * Dd + tid];
        const float wk = Wk[(size_t)kk * Dd + tid];
        const float wv = Wv[(size_t)kk * Dd + tid];
        #pragma unroll
        for (int i = 0; i < 4; ++i) {
            const float xv = xs[i][kk];
            aq[i] = fmaf(xv, wq, aq[i]);
            ak[i] = fmaf(xv, wk, ak[i]);
            av[i] = fmaf(xv, wv, av[i]);
        }
    }
    #pragma unroll
    for (int i = 0; i < 4; ++i) {
        qo[(size_t)(r0 + i) * Dd + tid] = aq[i];
        ko[(size_t)(r0 + i) * Dd + tid] = ak[i];
        vo[(size_t)(r0 + i) * Dd + tid] = av[i];
    }
}

// ---------------- Kernel 2: dk_act = silu(edge @ Wdk + bdk) via bf16 MFMA ----------------
// grid = MT/64 = 1152 blocks of 256 (4 waves). Block: 64 rows x 256 cols, K=256.
// wave wc handles cols [wc*64, wc*64+64): 4x4 tiles of 16x16, K-steps of 32.
__global__ __launch_bounds__(256) void dk_gemm_kernel(
    const float* __restrict__ edge, const short* __restrict__ Wt,
    const float* __restrict__ bdk, unsigned short* __restrict__ dkb)
{
    __shared__ short As[64][40];   // bf16 A-tile, +8 pad (80B rows, 16B-aligned, 2-way banks)
    const int tid  = threadIdx.x;
    const int lane = tid & 63;
    const int wc   = tid >> 6;      // wave id = column quadrant
    const int l15  = lane & 15;
    const int lq   = lane >> 4;     // 0..3
    const size_t Rbase = (size_t)blockIdx.x * 64;

    f32x4 acc[4][4];
    #pragma unroll
    for (int i = 0; i < 4; ++i)
        #pragma unroll
        for (int j = 0; j < 4; ++j)
            acc[i][j] = (f32x4){0.f, 0.f, 0.f, 0.f};

    const int sr = tid >> 2;          // staging row 0..63 (4 threads/row)
    const int sc = (tid & 3) * 8;     // staging col group
    const float* esrc = edge + (Rbase + sr) * 256 + sc;

    for (int kt = 0; kt < 8; ++kt) {
        const int k0 = kt * 32;
        const float4 f0 = *(const float4*)(esrc + k0);
        const float4 f1 = *(const float4*)(esrc + k0 + 4);
        short8 s;
        s[0]=f2bf(f0.x); s[1]=f2bf(f0.y); s[2]=f2bf(f0.z); s[3]=f2bf(f0.w);
        s[4]=f2bf(f1.x); s[5]=f2bf(f1.y); s[6]=f2bf(f1.z); s[7]=f2bf(f1.w);
        if (kt) __syncthreads();
        *(short8*)&As[sr][sc] = s;
        __syncthreads();

        short8 bfr[4];
        #pragma unroll
        for (int j = 0; j < 4; ++j)
            bfr[j] = *(const short8*)(Wt + (size_t)(wc*64 + j*16 + l15) * 256 + k0 + lq*8);
        #pragma unroll
        for (int i = 0; i < 4; ++i) {
            const short8 af = *(const short8*)&As[i*16 + l15][lq*8];
            #pragma unroll
            for (int j = 0; j < 4; ++j)
                acc[i][j] = __builtin_amdgcn_mfma_f32_16x16x32_bf16(af, bfr[j], acc[i][j], 0, 0, 0);
        }
    }

    float bv[4];
    #pragma unroll
    for (int j = 0; j < 4; ++j) bv[j] = bdk[wc*64 + j*16 + l15];

    #pragma unroll
    for (int i = 0; i < 4; ++i)
        #pragma unroll
        for (int rr = 0; rr < 4; ++rr) {
            const size_t R = Rbase + i*16 + lq*4 + rr;
            #pragma unroll
            for (int j = 0; j < 4; ++j) {
                const int d = wc*64 + j*16 + l15;
                dkb[R*256 + d] = (unsigned short)f2bf(silu_f(acc[i][j][rr] + bv[j]));
            }
        }
}

// ---------------- Kernel 3: attention reduce (reads precomputed dk_act) ----------------
__global__ __launch_bounds__(256) void attn_reduce_kernel(
    const float* __restrict__ q, const float* __restrict__ kmat, const float* __restrict__ vmat,
    const unsigned short* __restrict__ dkb, const int* __restrict__ mask,
    const float* __restrict__ dist, const float* __restrict__ vec,
    float* __restrict__ attn_out, float* __restrict__ t_out, float* __restrict__ sv_out)
{
    const int bn  = blockIdx.x;
    const int b   = bn / Nn;
    const int tid = threadIdx.x;

    __shared__ float scl[Nn];
    __shared__ float vcs[Nn][3];
    __shared__ int   mks[Nn];

    const float qv = q[(size_t)bn * Dd + tid];
    if (tid < Nn) {
        const int   mm = mask[(size_t)bn * Nn + tid];
        const float di = dist[(size_t)bn * Nn + tid];
        const float s  = (di < 5.0f) ? 0.5f * (cosf(di * PI_OVER_CUTOFF) + 1.0f) : 0.0f;
        scl[tid] = mm ? 0.0f : s;
        mks[tid] = mm;
    }
    for (int j = tid; j < Nn * 3; j += 256)
        (&vcs[0][0])[j] = vec[(size_t)bn * Nn * 3 + j];
    __syncthreads();

    float attn_acc = 0.0f, t0 = 0.0f, t1 = 0.0f, t2 = 0.0f;
    const float*          kb = kmat + (size_t)b * Nn * Dd + tid;
    const float*          vb = vmat + (size_t)b * Nn * Dd + tid;
    const unsigned short* db = dkb  + (size_t)bn * Nn * Dd + tid;

    for (int m = 0; m < Nn; ++m) {
        const float kvv = kb[(size_t)m * Dd];
        const float dkv = bf2f(db[(size_t)m * Dd]);
        float prod = qv * kvv * dkv;
        #pragma unroll
        for (int off = 16; off >= 1; off >>= 1)
            prod += __shfl_xor(prod, off, 32);
        const float p  = silu_f(prod) * scl[m];
        const float pv = p * vb[(size_t)m * Dd];
        attn_acc += pv;
        t0 = fmaf(vcs[m][0], pv, t0);
        t1 = fmaf(vcs[m][1], pv, t1);
        t2 = fmaf(vcs[m][2], pv, t2);
    }

    attn_out[(size_t)bn * Dd + tid] = attn_acc;
    t_out[((size_t)bn * 3 + 0) * Dd + tid] = t0;
    t_out[((size_t)bn * 3 + 1) * Dd + tid] = t1;
    t_out[((size_t)bn * 3 + 2) * Dd + tid] = t2;
    if (tid < 3) {
        float s = 0.0f;
        for (int m = 0; m < Nn; ++m) if (!mks[m]) s += vcs[m][tid];
        sv_out[(size_t)bn * 3 + tid] = s;
    }
}

// ---------------- Kernel 4: du = t@Wdu + svec*bdu ; w = du@Wdih (unchanged) ----------------
__global__ __launch_bounds__(256) void du_kernel(
    const float* __restrict__ t_in, const float* __restrict__ sv_in,
    const float* __restrict__ Wdu, const float* __restrict__ bdu,
    const float* __restrict__ Wdih,
    float* __restrict__ wsv, float* __restrict__ wtv)
{
    const int r0  = blockIdx.x * 4;
    const int tid = threadIdx.x;
    __shared__ float ts[12][Dd];
    __shared__ float dus[12][Dd];

    #pragma unroll
    for (int j = 0; j < 12; ++j)
        ts[j][tid] = t_in[((size_t)r0 * 3 + j) * Dd + tid];
    __syncthreads();

    float du[12];
    const float bd = bdu[tid];
    #pragma unroll
    for (int j = 0; j < 12; ++j) du[j] = sv_in[(size_t)r0 * 3 + j] * bd;

    for (int k4 = 0; k4 < 64; ++k4) {
        const float w0 = Wdu[(size_t)(k4 * 4 + 0) * Dd + tid];
        const float w1 = Wdu[(size_t)(k4 * 4 + 1) * Dd + tid];
        const float w2 = Wdu[(size_t)(k4 * 4 + 2) * Dd + tid];
        const float w3 = Wdu[(size_t)(k4 * 4 + 3) * Dd + tid];
        #pragma unroll
        for (int j = 0; j < 12; ++j) {
            const float4 e = *(const float4*)&ts[j][k4 * 4];
            du[j] = fmaf(e.x, w0, fmaf(e.y, w1, fmaf(e.z, w2, fmaf(e.w, w3, du[j]))));
        }
    }
    #pragma unroll
    for (int j = 0; j < 12; ++j) dus[j][tid] = du[j];
    __syncthreads();

    float as[12], at[12];
    #pragma unroll
    for (int j = 0; j < 12; ++j) { as[j] = 0.0f; at[j] = 0.0f; }

    for (int k4 = 0; k4 < 64; ++k4) {
        const float s0 = Wdih[(size_t)(k4 * 4 + 0) * 512 + tid];
        const float s1 = Wdih[(size_t)(k4 * 4 + 1) * 512 + tid];
        const float s2 = Wdih[(size_t)(k4 * 4 + 2) * 512 + tid];
        const float s3 = Wdih[(size_t)(k4 * 4 + 3) * 512 + tid];
        const float u0 = Wdih[(size_t)(k4 * 4 + 0) * 512 + 256 + tid];
        const float u1 = Wdih[(size_t)(k4 * 4 + 1) * 512 + 256 + tid];
        const float u2 = Wdih[(size_t)(k4 * 4 + 2) * 512 + 256 + tid];
        const float u3 = Wdih[(size_t)(k4 * 4 + 3) * 512 + 256 + tid];
        #pragma unroll
        for (int j = 0; j < 12; ++j) {
            const float4 e = *(const float4*)&dus[j][k4 * 4];
            as[j] = fmaf(e.x, s0, fmaf(e.y, s1, fmaf(e.z, s2, fmaf(e.w, s3, as[j]))));
            at[j] = fmaf(e.x, u0, fmaf(e.y, u1, fmaf(e.z, u2, fmaf(e.w, u3, at[j]))));
        }
    }
    #pragma unroll
    for (int j = 0; j < 12; ++j) {
        wsv[((size_t)r0 * 3 + j) * Dd + tid] = as[j];
        wtv[((size_t)r0 * 3 + j) * Dd + tid] = at[j];
    }
}

// ---------------- Kernel 5: ipe = silu(edge@Wea + bea) * sum_c ws.wt  (bf16 MFMA) ----------------
__global__ __launch_bounds__(256) void ea_ipe_kernel(
    const float* __restrict__ edge, const short* __restrict__ Wt,
    const float* __restrict__ bea,
    const float* __restrict__ wsv, const float* __restrict__ wtv,
    float* __restrict__ ipe)
{
    __shared__ short As[64][40];
    const int tid  = threadIdx.x;
    const int lane = tid & 63;
    const int wc   = tid >> 6;
    const int l15  = lane & 15;
    const int lq   = lane >> 4;
    const size_t Rbase = (size_t)blockIdx.x * 64;

    f32x4 acc[4][4];
    #pragma unroll
    for (int i = 0; i < 4; ++i)
        #pragma unroll
        for (int j = 0; j < 4; ++j)
            acc[i][j] = (f32x4){0.f, 0.f, 0.f, 0.f};

    const int sr = tid >> 2;
    const int sc = (tid & 3) * 8;
    const float* esrc = edge + (Rbase + sr) * 256 + sc;

    for (int kt = 0; kt < 8; ++kt) {
        const int k0 = kt * 32;
        const float4 f0 = *(const float4*)(esrc + k0);
        const float4 f1 = *(const float4*)(esrc + k0 + 4);
        short8 s;
        s[0]=f2bf(f0.x); s[1]=f2bf(f0.y); s[2]=f2bf(f0.z); s[3]=f2bf(f0.w);
        s[4]=f2bf(f1.x); s[5]=f2bf(f1.y); s[6]=f2bf(f1.z); s[7]=f2bf(f1.w);
        if (kt) __syncthreads();
        *(short8*)&As[sr][sc] = s;
        __syncthreads();

        short8 bfr[4];
        #pragma unroll
        for (int j = 0; j < 4; ++j)
            bfr[j] = *(const short8*)(Wt + (size_t)(wc*64 + j*16 + l15) * 256 + k0 + lq*8);
        #pragma unroll
        for (int i = 0; i < 4; ++i) {
            const short8 af = *(const short8*)&As[i*16 + l15][lq*8];
            #pragma unroll
            for (int j = 0; j < 4; ++j)
                acc[i][j] = __builtin_amdgcn_mfma_f32_16x16x32_bf16(af, bfr[j], acc[i][j], 0, 0, 0);
        }
    }

    float bvj[4];
    #pragma unroll
    for (int j = 0; j < 4; ++j) bvj[j] = bea[wc*64 + j*16 + l15];

    #pragma unroll
    for (int i = 0; i < 4; ++i)
        #pragma unroll
        for (int rr = 0; rr < 4; ++rr) {
            const unsigned R  = (unsigned)(Rbase + i*16 + lq*4 + rr);
            const unsigned bn = R / 96u;
            const unsigned m  = R - bn * 96u;
            const unsigned b  = bn / 96u;
            const unsigned wr = b * 96u + m;      // wt row (node (b,m))
            #pragma unroll
            for (int j = 0; j < 4; ++j) {
                const int d = wc*64 + j*16 + l15;
                const float ea = silu_f(acc[i][j][rr] + bvj[j]);
                const float sdot =
                    wsv[((size_t)bn * 3 + 0) * Dd + d] * wtv[((size_t)wr * 3 + 0) * Dd + d] +
                    wsv[((size_t)bn * 3 + 1) * Dd + d] * wtv[((size_t)wr * 3 + 1) * Dd + d] +
                    wsv[((size_t)bn * 3 + 2) * Dd + d] * wtv[((size_t)wr * 3 + 2) * Dd + d];
                ipe[(size_t)R * Dd + d] = ea * sdot;
            }
        }
}

extern "C" void kernel_launch(void* const* d_in, const int* in_sizes, int n_in,
                              void* d_out, int out_size, void* d_ws, size_t ws_size,
                              hipStream_t stream)
{
    const float* x    = (const float*)d_in[0];
    const float* vec  = (const float*)d_in[1];
    const float* dist = (const float*)d_in[2];
    const float* edge = (const float*)d_in[3];
    const int*   mask = (const int*)d_in[4];
    const float* Wq   = (const float*)d_in[5];
    const float* bq   = (const float*)d_in[6];
    const float* Wk   = (const float*)d_in[7];
    const float* bk   = (const float*)d_in[8];
    const float* Wv   = (const float*)d_in[9];
    const float* bv   = (const float*)d_in[10];
    const float* Wdk  = (const float*)d_in[11];
    const float* bdk  = (const float*)d_in[12];
    const float* Wdu  = (const float*)d_in[13];
    const float* bdu  = (const float*)d_in[14];
    const float* Wdih = (const float*)d_in[15];
    const float* Wea  = (const float*)d_in[16];
    const float* bea  = (const float*)d_in[17];

    float* out_attn = (float*)d_out;
    float* out_ipe  = out_attn + (size_t)BN * Dd;

    char* wsp = (char*)d_ws;
    float* qb  = (float*)wsp;                   wsp += (size_t)BN * Dd * 4;
    float* kb  = (float*)wsp;                   wsp += (size_t)BN * Dd * 4;
    float* vb  = (float*)wsp;                   wsp += (size_t)BN * Dd * 4;
    float* tb  = (float*)wsp;                   wsp += (size_t)BN * 3 * Dd * 4;
    float* svb = (float*)wsp;                   wsp += (size_t)BN * 4 * 4;
    float* wsvp= (float*)wsp;                   wsp += (size_t)BN * 3 * Dd * 4;
    float* wtvp= (float*)wsp;                   wsp += (size_t)BN * 3 * Dd * 4;
    short* Wtdk= (short*)wsp;                   wsp += (size_t)Dd * Dd * 2;
    short* Wtea= (short*)wsp;                   wsp += (size_t)Dd * Dd * 2;
    unsigned short* dkb = (unsigned short*)wsp; wsp += (size_t)MT * Dd * 2;

    wt_kernel<<<512, 256, 0, stream>>>(Wdk, Wea, Wtdk, Wtea);
    qkv_kernel<<<BN / 4, 256, 0, stream>>>(x, Wq, bq, Wk, bk, Wv, bv, qb, kb, vb);
    dk_gemm_kernel<<<MT / 64, 256, 0, stream>>>(edge, Wtdk, bdk, dkb);
    attn_reduce_kernel<<<BN, 256, 0, stream>>>(qb, kb, vb, dkb, mask, dist, vec,
                                               out_attn, tb, svb);
    du_kernel<<<BN / 4, 256, 0, stream>>>(tb, svb, Wdu, bdu, Wdih, wsvp, wtvp);
    ea_ipe_kernel<<<MT / 64, 256, 0, stream>>>(edge, Wtea, bea, wsvp, wtvp, out_ipe);
}

// Round 3
// 394.033 us; speedup vs baseline: 1.9009x; 1.0398x over previous
//
#include <hip/hip_runtime.h>
#include <hip/hip_bf16.h>
#include <math.h>

#define Bb 8
#define Nn 96
#define Dd 256
#define BN (Bb*Nn)      /* 768 */
#define MT (BN*Nn)      /* 73728 edge rows */
#define PI_OVER_CUTOFF 0.62831853071795864769f  /* pi/5 */

typedef short short8 __attribute__((ext_vector_type(8)));
typedef float f32x4  __attribute__((ext_vector_type(4)));

__device__ __forceinline__ float silu_f(float x){ return x / (1.0f + expf(-x)); }

__device__ __forceinline__ short f2bf(float f){
    __hip_bfloat16 h = __float2bfloat16(f);
    return __builtin_bit_cast(short, h);
}
__device__ __forceinline__ float bf2f(unsigned short u){
    union { unsigned uu; float ff; } a; a.uu = ((unsigned)u) << 16; return a.ff;
}

// ---------------- Kernel 0: Wt = bf16(W^T) for Wdk and Wea ----------------
__global__ __launch_bounds__(256) void wt_kernel(
    const float* __restrict__ Wdk, const float* __restrict__ Wea,
    short* __restrict__ Wtdk, short* __restrict__ Wtea)
{
    const int o   = blockIdx.x * 256 + threadIdx.x;
    const int sel = o >> 16;
    const int r   = o & 65535;
    const int n   = r >> 8, k = r & 255;
    const float* src = sel ? Wea : Wdk;
    short*       dst = sel ? Wtea : Wtdk;
    dst[r] = f2bf(src[k * 256 + n]);
}

// ---------------- Kernel 1: q,k,v projections ----------------
__global__ __launch_bounds__(256) void qkv_kernel(
    const float* __restrict__ x,
    const float* __restrict__ Wq, const float* __restrict__ bq,
    const float* __restrict__ Wk, const float* __restrict__ bk,
    const float* __restrict__ Wv, const float* __restrict__ bv,
    float* __restrict__ qo, float* __restrict__ ko, float* __restrict__ vo)
{
    __shared__ float xs[4][Dd];
    const int tid = threadIdx.x;
    const int r0  = blockIdx.x * 4;
    #pragma unroll
    for (int i = 0; i < 4; ++i) xs[i][tid] = x[(size_t)(r0 + i) * Dd + tid];
    __syncthreads();

    float aq[4], ak[4], av[4];
    const float bqv = bq[tid], bkv = bk[tid], bvv = bv[tid];
    #pragma unroll
    for (int i = 0; i < 4; ++i) { aq[i] = bqv; ak[i] = bkv; av[i] = bvv; }

    for (int kk = 0; kk < Dd; ++kk) {
        const float wq = Wq[(size_t)kk * Dd + tid];
        const float wk = Wk[(size_t)kk * Dd + tid];
        const float wv = Wv[(size_t)kk * Dd + tid];
        #pragma unroll
        for (int i = 0; i < 4; ++i) {
            const float xv = xs[i][kk];
            aq[i] = fmaf(xv, wq, aq[i]);
            ak[i] = fmaf(xv, wk, ak[i]);
            av[i] = fmaf(xv, wv, av[i]);
        }
    }
    #pragma unroll
    for (int i = 0; i < 4; ++i) {
        qo[(size_t)(r0 + i) * Dd + tid] = aq[i];
        ko[(size_t)(r0 + i) * Dd + tid] = ak[i];
        vo[(size_t)(r0 + i) * Dd + tid] = av[i];
    }
}

// ---------------- Kernel 2: fused dk-GEMM (MFMA) + attention + m-reductions ----------------
// One block per (b,n): 96 rows (m) x 256 cols (d), K=256. 4 waves, wave wc = cols [wc*64,+64).
// After GEMM: aw[m,h] = sum_{d in h} q*k*silu(dk); p = silu(aw)*scl; accumulate attn,t.
__global__ __launch_bounds__(256) void dk_attn_kernel(
    const float* __restrict__ edge, const short* __restrict__ Wt,
    const float* __restrict__ bdk,
    const float* __restrict__ q, const float* __restrict__ kmat, const float* __restrict__ vmat,
    const int* __restrict__ mask, const float* __restrict__ dist, const float* __restrict__ vec,
    float* __restrict__ attn_out, float* __restrict__ t_out, float* __restrict__ sv_out)
{
    __shared__ short As[96][40];      // bf16 A-slice (96 x 32), +8 pad
    __shared__ float scl[Nn];
    __shared__ float vcs[Nn][3];
    __shared__ int   mks[Nn];

    const int bn   = blockIdx.x;
    const int b    = bn / Nn;
    const int tid  = threadIdx.x;
    const int lane = tid & 63;
    const int wc   = tid >> 6;
    const int l15  = lane & 15;
    const int lq   = lane >> 4;

    if (tid < Nn) {
        const int   mm = mask[(size_t)bn * Nn + tid];
        const float di = dist[(size_t)bn * Nn + tid];
        const float s  = (di < 5.0f) ? 0.5f * (cosf(di * PI_OVER_CUTOFF) + 1.0f) : 0.0f;
        scl[tid] = mm ? 0.0f : s;
        mks[tid] = mm;
    }
    for (int j = tid; j < Nn * 3; j += 256)
        (&vcs[0][0])[j] = vec[(size_t)bn * Nn * 3 + j];

    int dj[4]; float qd[4], bv[4];
    #pragma unroll
    for (int j = 0; j < 4; ++j) {
        dj[j] = wc * 64 + j * 16 + l15;
        qd[j] = q[(size_t)bn * Dd + dj[j]];
        bv[j] = bdk[dj[j]];
    }

    f32x4 acc[6][4];
    #pragma unroll
    for (int i = 0; i < 6; ++i)
        #pragma unroll
        for (int j = 0; j < 4; ++j)
            acc[i][j] = (f32x4){0.f, 0.f, 0.f, 0.f};

    const float* eb = edge + (size_t)bn * Nn * Dd;
    const int sr = tid >> 3;          // 0..31
    const int sc = (tid & 7) * 4;     // 0,4,..,28

    for (int kt = 0; kt < 8; ++kt) {
        const int k0 = kt * 32;
        float4 f[3];
        #pragma unroll
        for (int u = 0; u < 3; ++u)
            f[u] = *(const float4*)(eb + (size_t)(sr + u * 32) * Dd + k0 + sc);

        if (kt) __syncthreads();
        #pragma unroll
        for (int u = 0; u < 3; ++u) {
            short4 s;
            s.x = f2bf(f[u].x); s.y = f2bf(f[u].y); s.z = f2bf(f[u].z); s.w = f2bf(f[u].w);
            *(short4*)&As[sr + u * 32][sc] = s;
        }
        __syncthreads();

        short8 bfr[4];
        #pragma unroll
        for (int j = 0; j < 4; ++j)
            bfr[j] = *(const short8*)(Wt + (size_t)dj[j] * 256 + k0 + lq * 8);
        #pragma unroll
        for (int i = 0; i < 6; ++i) {
            const short8 af = *(const short8*)&As[i * 16 + l15][lq * 8];
            #pragma unroll
            for (int j = 0; j < 4; ++j)
                acc[i][j] = __builtin_amdgcn_mfma_f32_16x16x32_bf16(af, bfr[j], acc[i][j], 0, 0, 0);
        }
    }

    float attnacc[4] = {0.f, 0.f, 0.f, 0.f};
    float tacc0[4]   = {0.f, 0.f, 0.f, 0.f};
    float tacc1[4]   = {0.f, 0.f, 0.f, 0.f};
    float tacc2[4]   = {0.f, 0.f, 0.f, 0.f};

    #pragma unroll
    for (int i = 0; i < 6; ++i) {
        #pragma unroll
        for (int rr = 0; rr < 4; ++rr) {
            const int m = i * 16 + lq * 4 + rr;
            const size_t krow = ((size_t)(b * Nn + m)) << 8;
            float kf[4], vf[4];
            #pragma unroll
            for (int j = 0; j < 4; ++j) {
                kf[j] = kmat[krow + dj[j]];
                vf[j] = vmat[krow + dj[j]];
            }
            float pr[4];
            #pragma unroll
            for (int j = 0; j < 4; ++j)
                pr[j] = silu_f(acc[i][j][rr] + bv[j]) * kf[j] * qd[j];
            float p0 = pr[0] + pr[1];
            float p1 = pr[2] + pr[3];
            #pragma unroll
            for (int off = 8; off; off >>= 1) {
                p0 += __shfl_xor(p0, off, 16);
                p1 += __shfl_xor(p1, off, 16);
            }
            const float sc2 = scl[m];
            p0 = silu_f(p0) * sc2;
            p1 = silu_f(p1) * sc2;
            const float vc0 = vcs[m][0], vc1 = vcs[m][1], vc2 = vcs[m][2];
            #pragma unroll
            for (int j = 0; j < 4; ++j) {
                const float pv = (j < 2 ? p0 : p1) * vf[j];
                attnacc[j] += pv;
                tacc0[j] = fmaf(vc0, pv, tacc0[j]);
                tacc1[j] = fmaf(vc1, pv, tacc1[j]);
                tacc2[j] = fmaf(vc2, pv, tacc2[j]);
            }
        }
    }

    #pragma unroll
    for (int j = 0; j < 4; ++j) {
        attnacc[j] += __shfl_xor(attnacc[j], 16, 64);
        attnacc[j] += __shfl_xor(attnacc[j], 32, 64);
        tacc0[j]   += __shfl_xor(tacc0[j], 16, 64);
        tacc0[j]   += __shfl_xor(tacc0[j], 32, 64);
        tacc1[j]   += __shfl_xor(tacc1[j], 16, 64);
        tacc1[j]   += __shfl_xor(tacc1[j], 32, 64);
        tacc2[j]   += __shfl_xor(tacc2[j], 16, 64);
        tacc2[j]   += __shfl_xor(tacc2[j], 32, 64);
    }
    if (lq == 0) {
        #pragma unroll
        for (int j = 0; j < 4; ++j) {
            attn_out[(size_t)bn * Dd + dj[j]] = attnacc[j];
            t_out[((size_t)bn * 3 + 0) * Dd + dj[j]] = tacc0[j];
            t_out[((size_t)bn * 3 + 1) * Dd + dj[j]] = tacc1[j];
            t_out[((size_t)bn * 3 + 2) * Dd + dj[j]] = tacc2[j];
        }
    }
    if (tid < 3) {
        float s = 0.0f;
        for (int m = 0; m < Nn; ++m) if (!mks[m]) s += vcs[m][tid];
        sv_out[(size_t)bn * 3 + tid] = s;
    }
}

// ---------------- Kernel 3: du = t@Wdu + svec*bdu ; w = du@Wdih -> ws (f32), wt (packed bf16) ----------------
__global__ __launch_bounds__(256) void du_kernel(
    const float* __restrict__ t_in, const float* __restrict__ sv_in,
    const float* __restrict__ Wdu, const float* __restrict__ bdu,
    const float* __restrict__ Wdih,
    float* __restrict__ wsv, unsigned short* __restrict__ wtp)
{
    const int r0  = blockIdx.x * 4;
    const int tid = threadIdx.x;
    __shared__ float ts[12][Dd];
    __shared__ float dus[12][Dd];

    #pragma unroll
    for (int j = 0; j < 12; ++j)
        ts[j][tid] = t_in[((size_t)r0 * 3 + j) * Dd + tid];
    __syncthreads();

    float du[12];
    const float bd = bdu[tid];
    #pragma unroll
    for (int j = 0; j < 12; ++j) du[j] = sv_in[(size_t)r0 * 3 + j] * bd;

    for (int k4 = 0; k4 < 64; ++k4) {
        const float w0 = Wdu[(size_t)(k4 * 4 + 0) * Dd + tid];
        const float w1 = Wdu[(size_t)(k4 * 4 + 1) * Dd + tid];
        const float w2 = Wdu[(size_t)(k4 * 4 + 2) * Dd + tid];
        const float w3 = Wdu[(size_t)(k4 * 4 + 3) * Dd + tid];
        #pragma unroll
        for (int j = 0; j < 12; ++j) {
            const float4 e = *(const float4*)&ts[j][k4 * 4];
            du[j] = fmaf(e.x, w0, fmaf(e.y, w1, fmaf(e.z, w2, fmaf(e.w, w3, du[j]))));
        }
    }
    #pragma unroll
    for (int j = 0; j < 12; ++j) dus[j][tid] = du[j];
    __syncthreads();

    float as[12], at[12];
    #pragma unroll
    for (int j = 0; j < 12; ++j) { as[j] = 0.0f; at[j] = 0.0f; }

    for (int k4 = 0; k4 < 64; ++k4) {
        const float s0 = Wdih[(size_t)(k4 * 4 + 0) * 512 + tid];
        const float s1 = Wdih[(size_t)(k4 * 4 + 1) * 512 + tid];
        const float s2 = Wdih[(size_t)(k4 * 4 + 2) * 512 + tid];
        const float s3 = Wdih[(size_t)(k4 * 4 + 3) * 512 + tid];
        const float u0 = Wdih[(size_t)(k4 * 4 + 0) * 512 + 256 + tid];
        const float u1 = Wdih[(size_t)(k4 * 4 + 1) * 512 + 256 + tid];
        const float u2 = Wdih[(size_t)(k4 * 4 + 2) * 512 + 256 + tid];
        const float u3 = Wdih[(size_t)(k4 * 4 + 3) * 512 + 256 + tid];
        #pragma unroll
        for (int j = 0; j < 12; ++j) {
            const float4 e = *(const float4*)&dus[j][k4 * 4];
            as[j] = fmaf(e.x, s0, fmaf(e.y, s1, fmaf(e.z, s2, fmaf(e.w, s3, as[j]))));
            at[j] = fmaf(e.x, u0, fmaf(e.y, u1, fmaf(e.z, u2, fmaf(e.w, u3, at[j]))));
        }
    }
    #pragma unroll
    for (int j = 0; j < 12; ++j)
        wsv[((size_t)r0 * 3 + j) * Dd + tid] = as[j];
    #pragma unroll
    for (int r = 0; r < 4; ++r) {
        ushort4 pk;
        pk.x = (unsigned short)f2bf(at[r * 3 + 0]);
        pk.y = (unsigned short)f2bf(at[r * 3 + 1]);
        pk.z = (unsigned short)f2bf(at[r * 3 + 2]);
        pk.w = 0;
        *(ushort4*)(wtp + ((size_t)(r0 + r) * Dd + tid) * 4) = pk;
    }
}

// ---------------- Kernel 4: ipe = silu(edge@Wea + bea) * sum_c ws.wt  (per-(b,n) MFMA) ----------------
__global__ __launch_bounds__(256) void ea_ipe_kernel(
    const float* __restrict__ edge, const short* __restrict__ Wt,
    const float* __restrict__ bea,
    const float* __restrict__ wsv, const unsigned short* __restrict__ wtp,
    float* __restrict__ ipe)
{
    __shared__ short As[96][40];
    const int bn   = blockIdx.x;
    const int b    = bn / Nn;
    const int tid  = threadIdx.x;
    const int lane = tid & 63;
    const int wc   = tid >> 6;
    const int l15  = lane & 15;
    const int lq   = lane >> 4;

    int dj[4]; float bvj[4], wsr0[4], wsr1[4], wsr2[4];
    #pragma unroll
    for (int j = 0; j < 4; ++j) {
        dj[j]   = wc * 64 + j * 16 + l15;
        bvj[j]  = bea[dj[j]];
        wsr0[j] = wsv[((size_t)bn * 3 + 0) * Dd + dj[j]];
        wsr1[j] = wsv[((size_t)bn * 3 + 1) * Dd + dj[j]];
        wsr2[j] = wsv[((size_t)bn * 3 + 2) * Dd + dj[j]];
    }

    f32x4 acc[6][4];
    #pragma unroll
    for (int i = 0; i < 6; ++i)
        #pragma unroll
        for (int j = 0; j < 4; ++j)
            acc[i][j] = (f32x4){0.f, 0.f, 0.f, 0.f};

    const float* eb = edge + (size_t)bn * Nn * Dd;
    const int sr = tid >> 3;
    const int sc = (tid & 7) * 4;

    for (int kt = 0; kt < 8; ++kt) {
        const int k0 = kt * 32;
        float4 f[3];
        #pragma unroll
        for (int u = 0; u < 3; ++u)
            f[u] = *(const float4*)(eb + (size_t)(sr + u * 32) * Dd + k0 + sc);

        if (kt) __syncthreads();
        #pragma unroll
        for (int u = 0; u < 3; ++u) {
            short4 s;
            s.x = f2bf(f[u].x); s.y = f2bf(f[u].y); s.z = f2bf(f[u].z); s.w = f2bf(f[u].w);
            *(short4*)&As[sr + u * 32][sc] = s;
        }
        __syncthreads();

        short8 bfr[4];
        #pragma unroll
        for (int j = 0; j < 4; ++j)
            bfr[j] = *(const short8*)(Wt + (size_t)dj[j] * 256 + k0 + lq * 8);
        #pragma unroll
        for (int i = 0; i < 6; ++i) {
            const short8 af = *(const short8*)&As[i * 16 + l15][lq * 8];
            #pragma unroll
            for (int j = 0; j < 4; ++j)
                acc[i][j] = __builtin_amdgcn_mfma_f32_16x16x32_bf16(af, bfr[j], acc[i][j], 0, 0, 0);
        }
    }

    #pragma unroll
    for (int i = 0; i < 6; ++i) {
        #pragma unroll
        for (int rr = 0; rr < 4; ++rr) {
            const int m  = i * 16 + lq * 4 + rr;
            const size_t wr = (size_t)(b * Nn + m);
            ushort4 w4[4];
            #pragma unroll
            for (int j = 0; j < 4; ++j)
                w4[j] = *(const ushort4*)(wtp + (wr * Dd + dj[j]) * 4);
            #pragma unroll
            for (int j = 0; j < 4; ++j) {
                const float ea = silu_f(acc[i][j][rr] + bvj[j]);
                const float sdot = wsr0[j] * bf2f(w4[j].x) +
                                   wsr1[j] * bf2f(w4[j].y) +
                                   wsr2[j] * bf2f(w4[j].z);
                ipe[((size_t)bn * Nn + m) * Dd + dj[j]] = ea * sdot;
            }
        }
    }
}

extern "C" void kernel_launch(void* const* d_in, const int* in_sizes, int n_in,
                              void* d_out, int out_size, void* d_ws, size_t ws_size,
                              hipStream_t stream)
{
    const float* x    = (const float*)d_in[0];
    const float* vec  = (const float*)d_in[1];
    const float* dist = (const float*)d_in[2];
    const float* edge = (const float*)d_in[3];
    const int*   mask = (const int*)d_in[4];
    const float* Wq   = (const float*)d_in[5];
    const float* bq   = (const float*)d_in[6];
    const float* Wk   = (const float*)d_in[7];
    const float* bk   = (const float*)d_in[8];
    const float* Wv   = (const float*)d_in[9];
    const float* bv   = (const float*)d_in[10];
    const float* Wdk  = (const float*)d_in[11];
    const float* bdk  = (const float*)d_in[12];
    const float* Wdu  = (const float*)d_in[13];
    const float* bdu  = (const float*)d_in[14];
    const float* Wdih = (const float*)d_in[15];
    const float* Wea  = (const float*)d_in[16];
    const float* bea  = (const float*)d_in[17];

    float* out_attn = (float*)d_out;
    float* out_ipe  = out_attn + (size_t)BN * Dd;

    char* wsp = (char*)d_ws;
    float* qb   = (float*)wsp;                   wsp += (size_t)BN * Dd * 4;
    float* kb   = (float*)wsp;                   wsp += (size_t)BN * Dd * 4;
    float* vb   = (float*)wsp;                   wsp += (size_t)BN * Dd * 4;
    float* tb   = (float*)wsp;                   wsp += (size_t)BN * 3 * Dd * 4;
    float* svb  = (float*)wsp;                   wsp += (size_t)BN * 4 * 4;
    float* wsvp = (float*)wsp;                   wsp += (size_t)BN * 3 * Dd * 4;
    unsigned short* wtpp = (unsigned short*)wsp; wsp += (size_t)BN * Dd * 4 * 2;
    short* Wtdk = (short*)wsp;                   wsp += (size_t)Dd * Dd * 2;
    short* Wtea = (short*)wsp;                   wsp += (size_t)Dd * Dd * 2;

    wt_kernel<<<512, 256, 0, stream>>>(Wdk, Wea, Wtdk, Wtea);
    qkv_kernel<<<BN / 4, 256, 0, stream>>>(x, Wq, bq, Wk, bk, Wv, bv, qb, kb, vb);
    dk_attn_kernel<<<BN, 256, 0, stream>>>(edge, Wtdk, bdk, qb, kb, vb, mask, dist, vec,
                                           out_attn, tb, svb);
    du_kernel<<<BN / 4, 256, 0, stream>>>(tb, svb, Wdu, bdu, Wdih, wsvp, wtpp);
    ea_ipe_kernel<<<BN, 256, 0, stream>>>(edge, Wtea, bea, wsvp, wtpp, out_ipe);
}

// Round 4
// 322.521 us; speedup vs baseline: 2.3224x; 1.2217x over previous
//
#include <hip/hip_runtime.h>
#include <hip/hip_bf16.h>
#include <math.h>

#define Bb 8
#define Nn 96
#define Dd 256
#define BN (Bb*Nn)      /* 768 */
#define MT (BN*Nn)      /* 73728 edge rows */
#define PI_OVER_CUTOFF 0.62831853071795864769f  /* pi/5 */

typedef short short8 __attribute__((ext_vector_type(8)));
typedef float f32x4  __attribute__((ext_vector_type(4)));

__device__ __forceinline__ float silu_f(float x){ return x / (1.0f + expf(-x)); }

__device__ __forceinline__ short f2bf(float f){
    __hip_bfloat16 h = __float2bfloat16(f);
    return __builtin_bit_cast(short, h);
}
__device__ __forceinline__ float bf2f(unsigned short u){
    union { unsigned uu; float ff; } a; a.uu = ((unsigned)u) << 16; return a.ff;
}

// async global->LDS, 16B per lane. LDS dest = base + lane*16 (wave-uniform base).
__device__ __forceinline__ void gll16(short* lds, const unsigned short* g){
    __builtin_amdgcn_global_load_lds(
        (const __attribute__((address_space(1))) unsigned int*)g,
        (__attribute__((address_space(3))) unsigned int*)lds, 16, 0, 0);
}

// ---------------- Kernel A: edge fp32 -> bf16 (streaming) ----------------
__global__ __launch_bounds__(256) void prep_kernel(
    const float* __restrict__ e, unsigned short* __restrict__ o)
{
    const size_t idx = ((size_t)blockIdx.x * 256 + threadIdx.x) * 8;
    const float4 a = *(const float4*)(e + idx);
    const float4 b = *(const float4*)(e + idx + 4);
    short8 s;
    s[0]=f2bf(a.x); s[1]=f2bf(a.y); s[2]=f2bf(a.z); s[3]=f2bf(a.w);
    s[4]=f2bf(b.x); s[5]=f2bf(b.y); s[6]=f2bf(b.z); s[7]=f2bf(b.w);
    *(short8*)(o + idx) = s;
}

// ---------------- Kernel 0: Wt = bf16(W^T) for Wdk and Wea ----------------
__global__ __launch_bounds__(256) void wt_kernel(
    const float* __restrict__ Wdk, const float* __restrict__ Wea,
    short* __restrict__ Wtdk, short* __restrict__ Wtea)
{
    const int o   = blockIdx.x * 256 + threadIdx.x;
    const int sel = o >> 16;
    const int r   = o & 65535;
    const int n   = r >> 8, k = r & 255;
    const float* src = sel ? Wea : Wdk;
    short*       dst = sel ? Wtea : Wtdk;
    dst[r] = f2bf(src[k * 256 + n]);
}

// ---------------- Kernel 1: q,k,v projections (1 matrix / block) ----------------
__global__ __launch_bounds__(256) void qkv_kernel(
    const float* __restrict__ x,
    const float* __restrict__ Wq, const float* __restrict__ bq,
    const float* __restrict__ Wk, const float* __restrict__ bk,
    const float* __restrict__ Wv, const float* __restrict__ bv,
    float* __restrict__ qo, float* __restrict__ ko, float* __restrict__ vo)
{
    __shared__ float xs[4][Dd];
    const int tid = threadIdx.x;
    const int sel = blockIdx.x % 3;
    const int r0  = (blockIdx.x / 3) * 4;
    const float* W  = sel == 0 ? Wq : (sel == 1 ? Wk : Wv);
    const float* bb = sel == 0 ? bq : (sel == 1 ? bk : bv);
    float*       ou = sel == 0 ? qo : (sel == 1 ? ko : vo);

    #pragma unroll
    for (int i = 0; i < 4; ++i) xs[i][tid] = x[(size_t)(r0 + i) * Dd + tid];
    __syncthreads();

    float a[4];
    const float bv0 = bb[tid];
    #pragma unroll
    for (int i = 0; i < 4; ++i) a[i] = bv0;

    for (int k4 = 0; k4 < 64; ++k4) {
        const float w0 = W[(size_t)(k4 * 4 + 0) * Dd + tid];
        const float w1 = W[(size_t)(k4 * 4 + 1) * Dd + tid];
        const float w2 = W[(size_t)(k4 * 4 + 2) * Dd + tid];
        const float w3 = W[(size_t)(k4 * 4 + 3) * Dd + tid];
        #pragma unroll
        for (int i = 0; i < 4; ++i) {
            const float4 e = *(const float4*)&xs[i][k4 * 4];
            a[i] = fmaf(e.x, w0, fmaf(e.y, w1, fmaf(e.z, w2, fmaf(e.w, w3, a[i]))));
        }
    }
    #pragma unroll
    for (int i = 0; i < 4; ++i) ou[(size_t)(r0 + i) * Dd + tid] = a[i];
}

// ---------------- Kernel 2: fused dk-GEMM (MFMA, async staged) + attention ----------------
// 512 thr = 8 waves; wave w owns cols [w*32,+32) = head w. 96 rows (m), K=256 in 2 chunks of 128.
__global__ __launch_bounds__(512, 4) void dk_attn_kernel(
    const unsigned short* __restrict__ ebf, const short* __restrict__ Wt,
    const float* __restrict__ bdk,
    const float* __restrict__ q, const float* __restrict__ kmat, const float* __restrict__ vmat,
    const int* __restrict__ mask, const float* __restrict__ dist, const float* __restrict__ vec,
    float* __restrict__ attn_out, float* __restrict__ t_out, float* __restrict__ sv_out)
{
    __shared__ short As[96 * 128];   // 24 KB, rows of 128 halves, XOR-swizzled segments
    __shared__ float scl[Nn];
    __shared__ float vcs[Nn][3];
    __shared__ int   mks[Nn];

    const int bn   = blockIdx.x;
    const int b    = bn / Nn;
    const int tid  = threadIdx.x;
    const int lane = tid & 63;
    const int w    = tid >> 6;
    const int l15  = lane & 15;
    const int lq   = lane >> 4;

    if (tid < Nn) {
        const int   mm = mask[(size_t)bn * Nn + tid];
        const float di = dist[(size_t)bn * Nn + tid];
        const float s  = (di < 5.0f) ? 0.5f * (cosf(di * PI_OVER_CUTOFF) + 1.0f) : 0.0f;
        scl[tid] = mm ? 0.0f : s;
        mks[tid] = mm;
    }
    for (int j = tid; j < Nn * 3; j += 512)
        (&vcs[0][0])[j] = vec[(size_t)bn * Nn * 3 + j];

    const int dj0 = w * 32 + l15, dj1 = dj0 + 16;
    const float qd0 = q[(size_t)bn * Dd + dj0], qd1 = q[(size_t)bn * Dd + dj1];
    const float bv0 = bdk[dj0], bv1 = bdk[dj1];

    f32x4 acc[6][2];
    #pragma unroll
    for (int i = 0; i < 6; ++i) { acc[i][0] = (f32x4){0.f,0.f,0.f,0.f}; acc[i][1] = (f32x4){0.f,0.f,0.f,0.f}; }

    const unsigned short* ebase = ebf + (size_t)bn * Nn * Dd;
    const int srow = (lane >> 4);          // 0..3 within chunk
    const int cs   = lane & 15;            // stored segment

    for (int kt = 0; kt < 2; ++kt) {
        if (kt) __syncthreads();
        #pragma unroll
        for (int u = 0; u < 3; ++u) {
            const int chunk = w * 3 + u;           // 0..23, 4 rows each
            const int r     = chunk * 4 + srow;
            const int gseg  = cs ^ (r & 7);
            gll16(As + chunk * 512, ebase + (size_t)r * Dd + kt * 128 + gseg * 8);
        }
        __syncthreads();

        short8 bf[2][4];
        #pragma unroll
        for (int s = 0; s < 4; ++s) {
            bf[0][s] = *(const short8*)(Wt + (size_t)dj0 * 256 + kt * 128 + s * 32 + lq * 8);
            bf[1][s] = *(const short8*)(Wt + (size_t)dj1 * 256 + kt * 128 + s * 32 + lq * 8);
        }
        #pragma unroll
        for (int i = 0; i < 6; ++i) {
            const int row = i * 16 + l15;
            const int rx  = row & 7;
            #pragma unroll
            for (int s = 0; s < 4; ++s) {
                const int pos = (s * 4 + lq) ^ rx;
                const short8 af = *(const short8*)&As[row * 128 + pos * 8];
                acc[i][0] = __builtin_amdgcn_mfma_f32_16x16x32_bf16(af, bf[0][s], acc[i][0], 0, 0, 0);
                acc[i][1] = __builtin_amdgcn_mfma_f32_16x16x32_bf16(af, bf[1][s], acc[i][1], 0, 0, 0);
            }
        }
    }

    float attn0 = 0.f, attn1 = 0.f;
    float t00=0.f, t01=0.f, t02=0.f, t10=0.f, t11=0.f, t12=0.f;

    #pragma unroll
    for (int i = 0; i < 6; ++i) {
        #pragma unroll
        for (int rr = 0; rr < 4; ++rr) {
            const int m = i * 16 + lq * 4 + rr;
            const size_t krow = ((size_t)(b * Nn + m)) << 8;
            const float k0 = kmat[krow + dj0], k1 = kmat[krow + dj1];
            const float v0 = vmat[krow + dj0], v1 = vmat[krow + dj1];
            float pr = silu_f(acc[i][0][rr] + bv0) * k0 * qd0
                     + silu_f(acc[i][1][rr] + bv1) * k1 * qd1;
            #pragma unroll
            for (int off = 8; off; off >>= 1)
                pr += __shfl_xor(pr, off, 16);
            const float p = silu_f(pr) * scl[m];
            const float pv0 = p * v0, pv1 = p * v1;
            attn0 += pv0; attn1 += pv1;
            const float c0 = vcs[m][0], c1 = vcs[m][1], c2 = vcs[m][2];
            t00 = fmaf(c0, pv0, t00); t01 = fmaf(c1, pv0, t01); t02 = fmaf(c2, pv0, t02);
            t10 = fmaf(c0, pv1, t10); t11 = fmaf(c1, pv1, t11); t12 = fmaf(c2, pv1, t12);
        }
    }

    attn0 += __shfl_xor(attn0, 16, 64); attn0 += __shfl_xor(attn0, 32, 64);
    attn1 += __shfl_xor(attn1, 16, 64); attn1 += __shfl_xor(attn1, 32, 64);
    t00 += __shfl_xor(t00, 16, 64); t00 += __shfl_xor(t00, 32, 64);
    t01 += __shfl_xor(t01, 16, 64); t01 += __shfl_xor(t01, 32, 64);
    t02 += __shfl_xor(t02, 16, 64); t02 += __shfl_xor(t02, 32, 64);
    t10 += __shfl_xor(t10, 16, 64); t10 += __shfl_xor(t10, 32, 64);
    t11 += __shfl_xor(t11, 16, 64); t11 += __shfl_xor(t11, 32, 64);
    t12 += __shfl_xor(t12, 16, 64); t12 += __shfl_xor(t12, 32, 64);

    if (lq == 0) {
        attn_out[(size_t)bn * Dd + dj0] = attn0;
        attn_out[(size_t)bn * Dd + dj1] = attn1;
        t_out[((size_t)bn * 3 + 0) * Dd + dj0] = t00;
        t_out[((size_t)bn * 3 + 1) * Dd + dj0] = t01;
        t_out[((size_t)bn * 3 + 2) * Dd + dj0] = t02;
        t_out[((size_t)bn * 3 + 0) * Dd + dj1] = t10;
        t_out[((size_t)bn * 3 + 1) * Dd + dj1] = t11;
        t_out[((size_t)bn * 3 + 2) * Dd + dj1] = t12;
    }
    if (tid < 3) {
        float s = 0.0f;
        for (int m = 0; m < Nn; ++m) if (!mks[m]) s += vcs[m][tid];
        sv_out[(size_t)bn * 3 + tid] = s;
    }
}

// ---------------- Kernel 3: du = t@Wdu + svec*bdu ; w = du@Wdih -> ws(f32), wt(bf16 packed) ----------------
__global__ __launch_bounds__(256) void du_kernel(
    const float* __restrict__ t_in, const float* __restrict__ sv_in,
    const float* __restrict__ Wdu, const float* __restrict__ bdu,
    const float* __restrict__ Wdih,
    float* __restrict__ wsv, unsigned short* __restrict__ wtp)
{
    const int r0  = blockIdx.x * 4;
    const int tid = threadIdx.x;
    __shared__ float ts[12][Dd];
    __shared__ float dus[12][Dd];

    #pragma unroll
    for (int j = 0; j < 12; ++j)
        ts[j][tid] = t_in[((size_t)r0 * 3 + j) * Dd + tid];
    __syncthreads();

    float du[12];
    const float bd = bdu[tid];
    #pragma unroll
    for (int j = 0; j < 12; ++j) du[j] = sv_in[(size_t)r0 * 3 + j] * bd;

    for (int k4 = 0; k4 < 64; ++k4) {
        const float w0 = Wdu[(size_t)(k4 * 4 + 0) * Dd + tid];
        const float w1 = Wdu[(size_t)(k4 * 4 + 1) * Dd + tid];
        const float w2 = Wdu[(size_t)(k4 * 4 + 2) * Dd + tid];
        const float w3 = Wdu[(size_t)(k4 * 4 + 3) * Dd + tid];
        #pragma unroll
        for (int j = 0; j < 12; ++j) {
            const float4 e = *(const float4*)&ts[j][k4 * 4];
            du[j] = fmaf(e.x, w0, fmaf(e.y, w1, fmaf(e.z, w2, fmaf(e.w, w3, du[j]))));
        }
    }
    #pragma unroll
    for (int j = 0; j < 12; ++j) dus[j][tid] = du[j];
    __syncthreads();

    float as[12], at[12];
    #pragma unroll
    for (int j = 0; j < 12; ++j) { as[j] = 0.0f; at[j] = 0.0f; }

    for (int k4 = 0; k4 < 64; ++k4) {
        const float s0 = Wdih[(size_t)(k4 * 4 + 0) * 512 + tid];
        const float s1 = Wdih[(size_t)(k4 * 4 + 1) * 512 + tid];
        const float s2 = Wdih[(size_t)(k4 * 4 + 2) * 512 + tid];
        const float s3 = Wdih[(size_t)(k4 * 4 + 3) * 512 + tid];
        const float u0 = Wdih[(size_t)(k4 * 4 + 0) * 512 + 256 + tid];
        const float u1 = Wdih[(size_t)(k4 * 4 + 1) * 512 + 256 + tid];
        const float u2 = Wdih[(size_t)(k4 * 4 + 2) * 512 + 256 + tid];
        const float u3 = Wdih[(size_t)(k4 * 4 + 3) * 512 + 256 + tid];
        #pragma unroll
        for (int j = 0; j < 12; ++j) {
            const float4 e = *(const float4*)&dus[j][k4 * 4];
            as[j] = fmaf(e.x, s0, fmaf(e.y, s1, fmaf(e.z, s2, fmaf(e.w, s3, as[j]))));
            at[j] = fmaf(e.x, u0, fmaf(e.y, u1, fmaf(e.z, u2, fmaf(e.w, u3, at[j]))));
        }
    }
    #pragma unroll
    for (int j = 0; j < 12; ++j)
        wsv[((size_t)r0 * 3 + j) * Dd + tid] = as[j];
    #pragma unroll
    for (int r = 0; r < 4; ++r) {
        ushort4 pk;
        pk.x = (unsigned short)f2bf(at[r * 3 + 0]);
        pk.y = (unsigned short)f2bf(at[r * 3 + 1]);
        pk.z = (unsigned short)f2bf(at[r * 3 + 2]);
        pk.w = 0;
        *(ushort4*)(wtp + ((size_t)(r0 + r) * Dd + tid) * 4) = pk;
    }
}

// ---------------- Kernel 4: ipe = silu(edge@Wea + bea) * sum_c ws.wt (async-staged MFMA) ----------------
__global__ __launch_bounds__(512, 4) void ea_ipe_kernel(
    const unsigned short* __restrict__ ebf, const short* __restrict__ Wt,
    const float* __restrict__ bea,
    const float* __restrict__ wsv, const unsigned short* __restrict__ wtp,
    float* __restrict__ ipe)
{
    __shared__ short As[96 * 128];
    const int bn   = blockIdx.x;
    const int b    = bn / Nn;
    const int tid  = threadIdx.x;
    const int lane = tid & 63;
    const int w    = tid >> 6;
    const int l15  = lane & 15;
    const int lq   = lane >> 4;

    const int dj0 = w * 32 + l15, dj1 = dj0 + 16;
    const float be0 = bea[dj0], be1 = bea[dj1];
    const float ws00 = wsv[((size_t)bn*3+0)*Dd + dj0], ws01 = wsv[((size_t)bn*3+1)*Dd + dj0],
                ws02 = wsv[((size_t)bn*3+2)*Dd + dj0];
    const float ws10 = wsv[((size_t)bn*3+0)*Dd + dj1], ws11 = wsv[((size_t)bn*3+1)*Dd + dj1],
                ws12 = wsv[((size_t)bn*3+2)*Dd + dj1];

    f32x4 acc[6][2];
    #pragma unroll
    for (int i = 0; i < 6; ++i) { acc[i][0] = (f32x4){0.f,0.f,0.f,0.f}; acc[i][1] = (f32x4){0.f,0.f,0.f,0.f}; }

    const unsigned short* ebase = ebf + (size_t)bn * Nn * Dd;
    const int srow = (lane >> 4);
    const int cs   = lane & 15;

    for (int kt = 0; kt < 2; ++kt) {
        if (kt) __syncthreads();
        #pragma unroll
        for (int u = 0; u < 3; ++u) {
            const int chunk = w * 3 + u;
            const int r     = chunk * 4 + srow;
            const int gseg  = cs ^ (r & 7);
            gll16(As + chunk * 512, ebase + (size_t)r * Dd + kt * 128 + gseg * 8);
        }
        __syncthreads();

        short8 bf[2][4];
        #pragma unroll
        for (int s = 0; s < 4; ++s) {
            bf[0][s] = *(const short8*)(Wt + (size_t)dj0 * 256 + kt * 128 + s * 32 + lq * 8);
            bf[1][s] = *(const short8*)(Wt + (size_t)dj1 * 256 + kt * 128 + s * 32 + lq * 8);
        }
        #pragma unroll
        for (int i = 0; i < 6; ++i) {
            const int row = i * 16 + l15;
            const int rx  = row & 7;
            #pragma unroll
            for (int s = 0; s < 4; ++s) {
                const int pos = (s * 4 + lq) ^ rx;
                const short8 af = *(const short8*)&As[row * 128 + pos * 8];
                acc[i][0] = __builtin_amdgcn_mfma_f32_16x16x32_bf16(af, bf[0][s], acc[i][0], 0, 0, 0);
                acc[i][1] = __builtin_amdgcn_mfma_f32_16x16x32_bf16(af, bf[1][s], acc[i][1], 0, 0, 0);
            }
        }
    }

    #pragma unroll
    for (int i = 0; i < 6; ++i) {
        #pragma unroll
        for (int rr = 0; rr < 4; ++rr) {
            const int m = i * 16 + lq * 4 + rr;
            const size_t wr = (size_t)(b * Nn + m);
            const ushort4 w40 = *(const ushort4*)(wtp + (wr * Dd + dj0) * 4);
            const ushort4 w41 = *(const ushort4*)(wtp + (wr * Dd + dj1) * 4);
            const float ea0 = silu_f(acc[i][0][rr] + be0);
            const float ea1 = silu_f(acc[i][1][rr] + be1);
            const float sd0 = ws00 * bf2f(w40.x) + ws01 * bf2f(w40.y) + ws02 * bf2f(w40.z);
            const float sd1 = ws10 * bf2f(w41.x) + ws11 * bf2f(w41.y) + ws12 * bf2f(w41.z);
            ipe[((size_t)bn * Nn + m) * Dd + dj0] = ea0 * sd0;
            ipe[((size_t)bn * Nn + m) * Dd + dj1] = ea1 * sd1;
        }
    }
}

extern "C" void kernel_launch(void* const* d_in, const int* in_sizes, int n_in,
                              void* d_out, int out_size, void* d_ws, size_t ws_size,
                              hipStream_t stream)
{
    const float* x    = (const float*)d_in[0];
    const float* vec  = (const float*)d_in[1];
    const float* dist = (const float*)d_in[2];
    const float* edge = (const float*)d_in[3];
    const int*   mask = (const int*)d_in[4];
    const float* Wq   = (const float*)d_in[5];
    const float* bq   = (const float*)d_in[6];
    const float* Wk   = (const float*)d_in[7];
    const float* bk   = (const float*)d_in[8];
    const float* Wv   = (const float*)d_in[9];
    const float* bv   = (const float*)d_in[10];
    const float* Wdk  = (const float*)d_in[11];
    const float* bdk  = (const float*)d_in[12];
    const float* Wdu  = (const float*)d_in[13];
    const float* bdu  = (const float*)d_in[14];
    const float* Wdih = (const float*)d_in[15];
    const float* Wea  = (const float*)d_in[16];
    const float* bea  = (const float*)d_in[17];

    float* out_attn = (float*)d_out;
    float* out_ipe  = out_attn + (size_t)BN * Dd;

    char* wsp = (char*)d_ws;
    unsigned short* ebf  = (unsigned short*)wsp;  wsp += (size_t)MT * Dd * 2;
    float* qb   = (float*)wsp;                    wsp += (size_t)BN * Dd * 4;
    float* kb   = (float*)wsp;                    wsp += (size_t)BN * Dd * 4;
    float* vb   = (float*)wsp;                    wsp += (size_t)BN * Dd * 4;
    float* tb   = (float*)wsp;                    wsp += (size_t)BN * 3 * Dd * 4;
    float* svb  = (float*)wsp;                    wsp += (size_t)BN * 4 * 4;
    float* wsvp = (float*)wsp;                    wsp += (size_t)BN * 3 * Dd * 4;
    unsigned short* wtpp = (unsigned short*)wsp;  wsp += (size_t)BN * Dd * 4 * 2;
    short* Wtdk = (short*)wsp;                    wsp += (size_t)Dd * Dd * 2;
    short* Wtea = (short*)wsp;                    wsp += (size_t)Dd * Dd * 2;

    prep_kernel<<<MT * Dd / (256 * 8), 256, 0, stream>>>(edge, ebf);
    wt_kernel<<<512, 256, 0, stream>>>(Wdk, Wea, Wtdk, Wtea);
    qkv_kernel<<<(BN / 4) * 3, 256, 0, stream>>>(x, Wq, bq, Wk, bk, Wv, bv, qb, kb, vb);
    dk_attn_kernel<<<BN, 512, 0, stream>>>(ebf, Wtdk, bdk, qb, kb, vb, mask, dist, vec,
                                           out_attn, tb, svb);
    du_kernel<<<BN / 4, 256, 0, stream>>>(tb, svb, Wdu, bdu, Wdih, wsvp, wtpp);
    ea_ipe_kernel<<<BN, 512, 0, stream>>>(ebf, Wtea, bea, wsvp, wtpp, out_ipe);
}

// Round 5
// 293.897 us; speedup vs baseline: 2.5486x; 1.0974x over previous
//
#include <hip/hip_runtime.h>
#include <hip/hip_bf16.h>
#include <math.h>

#define Bb 8
#define Nn 96
#define Dd 256
#define BN (Bb*Nn)      /* 768 */
#define MT (BN*Nn)      /* 73728 edge rows */
#define PI_OVER_CUTOFF 0.62831853071795864769f  /* pi/5 */

#define PREP_BLOCKS (MT * Dd / 2048)   /* 9216 */
#define WT_BLOCKS   512
#define QKV_BLOCKS  ((BN / 2) * 3)     /* 1152 */

typedef short short8 __attribute__((ext_vector_type(8)));
typedef float f32x4  __attribute__((ext_vector_type(4)));

__device__ __forceinline__ float silu_f(float x){ return x / (1.0f + expf(-x)); }

__device__ __forceinline__ short f2bf(float f){
    __hip_bfloat16 h = __float2bfloat16(f);
    return __builtin_bit_cast(short, h);
}
__device__ __forceinline__ float bf2f(unsigned short u){
    union { unsigned uu; float ff; } a; a.uu = ((unsigned)u) << 16; return a.ff;
}

// async global->LDS, 16B per lane. LDS dest = base + lane*16 (wave-uniform base).
__device__ __forceinline__ void gll16(short* lds, const unsigned short* g){
    __builtin_amdgcn_global_load_lds(
        (const __attribute__((address_space(1))) unsigned int*)g,
        (__attribute__((address_space(3))) unsigned int*)lds, 16, 0, 0);
}

// ---------------- Kernel 1: setup = prep (edge->bf16) + wt (W^T bf16) + qkv ----------------
__global__ __launch_bounds__(256) void setup_kernel(
    const float* __restrict__ edge, unsigned short* __restrict__ ebf,
    const float* __restrict__ Wdk, const float* __restrict__ Wea,
    short* __restrict__ Wtdk, short* __restrict__ Wtea,
    const float* __restrict__ x,
    const float* __restrict__ Wq, const float* __restrict__ bq,
    const float* __restrict__ Wk, const float* __restrict__ bk,
    const float* __restrict__ Wv, const float* __restrict__ bv,
    float* __restrict__ qo, float* __restrict__ ko, float* __restrict__ vo)
{
    const int blk = blockIdx.x;
    const int tid = threadIdx.x;

    if (blk < PREP_BLOCKS) {
        // ---- edge fp32 -> bf16, streaming ----
        const size_t idx = ((size_t)blk * 256 + tid) * 8;
        const float4 a = *(const float4*)(edge + idx);
        const float4 b = *(const float4*)(edge + idx + 4);
        short8 s;
        s[0]=f2bf(a.x); s[1]=f2bf(a.y); s[2]=f2bf(a.z); s[3]=f2bf(a.w);
        s[4]=f2bf(b.x); s[5]=f2bf(b.y); s[6]=f2bf(b.z); s[7]=f2bf(b.w);
        *(short8*)(ebf + idx) = s;
        return;
    }
    if (blk < PREP_BLOCKS + WT_BLOCKS) {
        // ---- Wt = bf16(W^T) ----
        const int o   = (blk - PREP_BLOCKS) * 256 + tid;
        const int sel = o >> 16;
        const int r   = o & 65535;
        const int n   = r >> 8, k = r & 255;
        const float* src = sel ? Wea : Wdk;
        short*       dst = sel ? Wtea : Wtdk;
        dst[r] = f2bf(src[k * 256 + n]);
        return;
    }

    // ---- qkv: 2 rows, 1 matrix per block ----
    __shared__ float xs[2][Dd];
    const int idx = blk - PREP_BLOCKS - WT_BLOCKS;
    const int sel = idx % 3;
    const int r0  = (idx / 3) * 2;
    const float* W  = sel == 0 ? Wq : (sel == 1 ? Wk : Wv);
    const float* bb = sel == 0 ? bq : (sel == 1 ? bk : bv);
    float*       ou = sel == 0 ? qo : (sel == 1 ? ko : vo);

    #pragma unroll
    for (int i = 0; i < 2; ++i) xs[i][tid] = x[(size_t)(r0 + i) * Dd + tid];
    __syncthreads();

    float a0, a1;
    a0 = a1 = bb[tid];
    for (int k4 = 0; k4 < 64; ++k4) {
        const float w0 = W[(size_t)(k4 * 4 + 0) * Dd + tid];
        const float w1 = W[(size_t)(k4 * 4 + 1) * Dd + tid];
        const float w2 = W[(size_t)(k4 * 4 + 2) * Dd + tid];
        const float w3 = W[(size_t)(k4 * 4 + 3) * Dd + tid];
        const float4 e0 = *(const float4*)&xs[0][k4 * 4];
        const float4 e1 = *(const float4*)&xs[1][k4 * 4];
        a0 = fmaf(e0.x, w0, fmaf(e0.y, w1, fmaf(e0.z, w2, fmaf(e0.w, w3, a0))));
        a1 = fmaf(e1.x, w0, fmaf(e1.y, w1, fmaf(e1.z, w2, fmaf(e1.w, w3, a1))));
    }
    ou[(size_t)r0 * Dd + tid]       = a0;
    ou[(size_t)(r0 + 1) * Dd + tid] = a1;
}

// ---------------- Kernel 2: fused dk-GEMM (MFMA, async staged) + attention ----------------
// 512 thr = 8 waves; wave w owns cols [w*32,+32) = head w. 96 rows (m), K=256 in 2 chunks of 128.
__global__ __launch_bounds__(512, 4) void dk_attn_kernel(
    const unsigned short* __restrict__ ebf, const short* __restrict__ Wt,
    const float* __restrict__ bdk,
    const float* __restrict__ q, const float* __restrict__ kmat, const float* __restrict__ vmat,
    const int* __restrict__ mask, const float* __restrict__ dist, const float* __restrict__ vec,
    float* __restrict__ attn_out, float* __restrict__ t_out, float* __restrict__ sv_out)
{
    __shared__ short As[96 * 128];   // 24 KB, rows of 128 halves, XOR-swizzled segments
    __shared__ float scl[Nn];
    __shared__ float vcs[Nn][3];
    __shared__ int   mks[Nn];

    const int bn   = blockIdx.x;
    const int b    = bn / Nn;
    const int tid  = threadIdx.x;
    const int lane = tid & 63;
    const int w    = tid >> 6;
    const int l15  = lane & 15;
    const int lq   = lane >> 4;

    if (tid < Nn) {
        const int   mm = mask[(size_t)bn * Nn + tid];
        const float di = dist[(size_t)bn * Nn + tid];
        const float s  = (di < 5.0f) ? 0.5f * (cosf(di * PI_OVER_CUTOFF) + 1.0f) : 0.0f;
        scl[tid] = mm ? 0.0f : s;
        mks[tid] = mm;
    }
    for (int j = tid; j < Nn * 3; j += 512)
        (&vcs[0][0])[j] = vec[(size_t)bn * Nn * 3 + j];

    const int dj0 = w * 32 + l15, dj1 = dj0 + 16;
    const float qd0 = q[(size_t)bn * Dd + dj0], qd1 = q[(size_t)bn * Dd + dj1];
    const float bv0 = bdk[dj0], bv1 = bdk[dj1];

    f32x4 acc[6][2];
    #pragma unroll
    for (int i = 0; i < 6; ++i) { acc[i][0] = (f32x4){0.f,0.f,0.f,0.f}; acc[i][1] = (f32x4){0.f,0.f,0.f,0.f}; }

    const unsigned short* ebase = ebf + (size_t)bn * Nn * Dd;
    const int srow = (lane >> 4);          // 0..3 within chunk
    const int cs   = lane & 15;            // stored segment

    for (int kt = 0; kt < 2; ++kt) {
        if (kt) __syncthreads();
        #pragma unroll
        for (int u = 0; u < 3; ++u) {
            const int chunk = w * 3 + u;           // 0..23, 4 rows each
            const int r     = chunk * 4 + srow;
            const int gseg  = cs ^ (r & 7);
            gll16(As + chunk * 512, ebase + (size_t)r * Dd + kt * 128 + gseg * 8);
        }
        __syncthreads();

        short8 bf[2][4];
        #pragma unroll
        for (int s = 0; s < 4; ++s) {
            bf[0][s] = *(const short8*)(Wt + (size_t)dj0 * 256 + kt * 128 + s * 32 + lq * 8);
            bf[1][s] = *(const short8*)(Wt + (size_t)dj1 * 256 + kt * 128 + s * 32 + lq * 8);
        }
        #pragma unroll
        for (int i = 0; i < 6; ++i) {
            const int row = i * 16 + l15;
            const int rx  = row & 7;
            #pragma unroll
            for (int s = 0; s < 4; ++s) {
                const int pos = (s * 4 + lq) ^ rx;
                const short8 af = *(const short8*)&As[row * 128 + pos * 8];
                acc[i][0] = __builtin_amdgcn_mfma_f32_16x16x32_bf16(af, bf[0][s], acc[i][0], 0, 0, 0);
                acc[i][1] = __builtin_amdgcn_mfma_f32_16x16x32_bf16(af, bf[1][s], acc[i][1], 0, 0, 0);
            }
        }
    }

    float attn0 = 0.f, attn1 = 0.f;
    float t00=0.f, t01=0.f, t02=0.f, t10=0.f, t11=0.f, t12=0.f;

    #pragma unroll
    for (int i = 0; i < 6; ++i) {
        #pragma unroll
        for (int rr = 0; rr < 4; ++rr) {
            const int m = i * 16 + lq * 4 + rr;
            const size_t krow = ((size_t)(b * Nn + m)) << 8;
            const float k0 = kmat[krow + dj0], k1 = kmat[krow + dj1];
            const float v0 = vmat[krow + dj0], v1 = vmat[krow + dj1];
            float pr = silu_f(acc[i][0][rr] + bv0) * k0 * qd0
                     + silu_f(acc[i][1][rr] + bv1) * k1 * qd1;
            #pragma unroll
            for (int off = 8; off; off >>= 1)
                pr += __shfl_xor(pr, off, 16);
            const float p = silu_f(pr) * scl[m];
            const float pv0 = p * v0, pv1 = p * v1;
            attn0 += pv0; attn1 += pv1;
            const float c0 = vcs[m][0], c1 = vcs[m][1], c2 = vcs[m][2];
            t00 = fmaf(c0, pv0, t00); t01 = fmaf(c1, pv0, t01); t02 = fmaf(c2, pv0, t02);
            t10 = fmaf(c0, pv1, t10); t11 = fmaf(c1, pv1, t11); t12 = fmaf(c2, pv1, t12);
        }
    }

    attn0 += __shfl_xor(attn0, 16, 64); attn0 += __shfl_xor(attn0, 32, 64);
    attn1 += __shfl_xor(attn1, 16, 64); attn1 += __shfl_xor(attn1, 32, 64);
    t00 += __shfl_xor(t00, 16, 64); t00 += __shfl_xor(t00, 32, 64);
    t01 += __shfl_xor(t01, 16, 64); t01 += __shfl_xor(t01, 32, 64);
    t02 += __shfl_xor(t02, 16, 64); t02 += __shfl_xor(t02, 32, 64);
    t10 += __shfl_xor(t10, 16, 64); t10 += __shfl_xor(t10, 32, 64);
    t11 += __shfl_xor(t11, 16, 64); t11 += __shfl_xor(t11, 32, 64);
    t12 += __shfl_xor(t12, 16, 64); t12 += __shfl_xor(t12, 32, 64);

    if (lq == 0) {
        attn_out[(size_t)bn * Dd + dj0] = attn0;
        attn_out[(size_t)bn * Dd + dj1] = attn1;
        t_out[((size_t)bn * 3 + 0) * Dd + dj0] = t00;
        t_out[((size_t)bn * 3 + 1) * Dd + dj0] = t01;
        t_out[((size_t)bn * 3 + 2) * Dd + dj0] = t02;
        t_out[((size_t)bn * 3 + 0) * Dd + dj1] = t10;
        t_out[((size_t)bn * 3 + 1) * Dd + dj1] = t11;
        t_out[((size_t)bn * 3 + 2) * Dd + dj1] = t12;
    }
    if (tid < 3) {
        float s = 0.0f;
        for (int m = 0; m < Nn; ++m) if (!mks[m]) s += vcs[m][tid];
        sv_out[(size_t)bn * 3 + tid] = s;
    }
}

// ---------------- Kernel 3: du = t@Wdu + svec*bdu ; w = du@Wdih -> ws(f32), wt(bf16 packed) ----
// One bn-row (3 c-rows) per block -> 768 blocks for latency hiding.
__global__ __launch_bounds__(256) void du_kernel(
    const float* __restrict__ t_in, const float* __restrict__ sv_in,
    const float* __restrict__ Wdu, const float* __restrict__ bdu,
    const float* __restrict__ Wdih,
    float* __restrict__ wsv, unsigned short* __restrict__ wtp)
{
    const int bn  = blockIdx.x;
    const int tid = threadIdx.x;
    __shared__ float ts[3][Dd];
    __shared__ float dus[3][Dd];

    #pragma unroll
    for (int j = 0; j < 3; ++j)
        ts[j][tid] = t_in[((size_t)bn * 3 + j) * Dd + tid];
    __syncthreads();

    float du[3];
    const float bd = bdu[tid];
    #pragma unroll
    for (int j = 0; j < 3; ++j) du[j] = sv_in[(size_t)bn * 3 + j] * bd;

    for (int k4 = 0; k4 < 64; ++k4) {
        const float w0 = Wdu[(size_t)(k4 * 4 + 0) * Dd + tid];
        const float w1 = Wdu[(size_t)(k4 * 4 + 1) * Dd + tid];
        const float w2 = Wdu[(size_t)(k4 * 4 + 2) * Dd + tid];
        const float w3 = Wdu[(size_t)(k4 * 4 + 3) * Dd + tid];
        #pragma unroll
        for (int j = 0; j < 3; ++j) {
            const float4 e = *(const float4*)&ts[j][k4 * 4];
            du[j] = fmaf(e.x, w0, fmaf(e.y, w1, fmaf(e.z, w2, fmaf(e.w, w3, du[j]))));
        }
    }
    #pragma unroll
    for (int j = 0; j < 3; ++j) dus[j][tid] = du[j];
    __syncthreads();

    float as[3] = {0.f, 0.f, 0.f}, at[3] = {0.f, 0.f, 0.f};

    for (int k4 = 0; k4 < 64; ++k4) {
        const float s0 = Wdih[(size_t)(k4 * 4 + 0) * 512 + tid];
        const float s1 = Wdih[(size_t)(k4 * 4 + 1) * 512 + tid];
        const float s2 = Wdih[(size_t)(k4 * 4 + 2) * 512 + tid];
        const float s3 = Wdih[(size_t)(k4 * 4 + 3) * 512 + tid];
        const float u0 = Wdih[(size_t)(k4 * 4 + 0) * 512 + 256 + tid];
        const float u1 = Wdih[(size_t)(k4 * 4 + 1) * 512 + 256 + tid];
        const float u2 = Wdih[(size_t)(k4 * 4 + 2) * 512 + 256 + tid];
        const float u3 = Wdih[(size_t)(k4 * 4 + 3) * 512 + 256 + tid];
        #pragma unroll
        for (int j = 0; j < 3; ++j) {
            const float4 e = *(const float4*)&dus[j][k4 * 4];
            as[j] = fmaf(e.x, s0, fmaf(e.y, s1, fmaf(e.z, s2, fmaf(e.w, s3, as[j]))));
            at[j] = fmaf(e.x, u0, fmaf(e.y, u1, fmaf(e.z, u2, fmaf(e.w, u3, at[j]))));
        }
    }
    #pragma unroll
    for (int j = 0; j < 3; ++j)
        wsv[((size_t)bn * 3 + j) * Dd + tid] = as[j];
    ushort4 pk;
    pk.x = (unsigned short)f2bf(at[0]);
    pk.y = (unsigned short)f2bf(at[1]);
    pk.z = (unsigned short)f2bf(at[2]);
    pk.w = 0;
    *(ushort4*)(wtp + ((size_t)bn * Dd + tid) * 4) = pk;
}

// ---------------- Kernel 4: ipe = silu(edge@Wea + bea) * sum_c ws.wt (async-staged MFMA) ----------------
__global__ __launch_bounds__(512, 4) void ea_ipe_kernel(
    const unsigned short* __restrict__ ebf, const short* __restrict__ Wt,
    const float* __restrict__ bea,
    const float* __restrict__ wsv, const unsigned short* __restrict__ wtp,
    float* __restrict__ ipe)
{
    __shared__ short As[96 * 128];
    const int bn   = blockIdx.x;
    const int b    = bn / Nn;
    const int tid  = threadIdx.x;
    const int lane = tid & 63;
    const int w    = tid >> 6;
    const int l15  = lane & 15;
    const int lq   = lane >> 4;

    const int dj0 = w * 32 + l15, dj1 = dj0 + 16;
    const float be0 = bea[dj0], be1 = bea[dj1];
    const float ws00 = wsv[((size_t)bn*3+0)*Dd + dj0], ws01 = wsv[((size_t)bn*3+1)*Dd + dj0],
                ws02 = wsv[((size_t)bn*3+2)*Dd + dj0];
    const float ws10 = wsv[((size_t)bn*3+0)*Dd + dj1], ws11 = wsv[((size_t)bn*3+1)*Dd + dj1],
                ws12 = wsv[((size_t)bn*3+2)*Dd + dj1];

    f32x4 acc[6][2];
    #pragma unroll
    for (int i = 0; i < 6; ++i) { acc[i][0] = (f32x4){0.f,0.f,0.f,0.f}; acc[i][1] = (f32x4){0.f,0.f,0.f,0.f}; }

    const unsigned short* ebase = ebf + (size_t)bn * Nn * Dd;
    const int srow = (lane >> 4);
    const int cs   = lane & 15;

    for (int kt = 0; kt < 2; ++kt) {
        if (kt) __syncthreads();
        #pragma unroll
        for (int u = 0; u < 3; ++u) {
            const int chunk = w * 3 + u;
            const int r     = chunk * 4 + srow;
            const int gseg  = cs ^ (r & 7);
            gll16(As + chunk * 512, ebase + (size_t)r * Dd + kt * 128 + gseg * 8);
        }
        __syncthreads();

        short8 bf[2][4];
        #pragma unroll
        for (int s = 0; s < 4; ++s) {
            bf[0][s] = *(const short8*)(Wt + (size_t)dj0 * 256 + kt * 128 + s * 32 + lq * 8);
            bf[1][s] = *(const short8*)(Wt + (size_t)dj1 * 256 + kt * 128 + s * 32 + lq * 8);
        }
        #pragma unroll
        for (int i = 0; i < 6; ++i) {
            const int row = i * 16 + l15;
            const int rx  = row & 7;
            #pragma unroll
            for (int s = 0; s < 4; ++s) {
                const int pos = (s * 4 + lq) ^ rx;
                const short8 af = *(const short8*)&As[row * 128 + pos * 8];
                acc[i][0] = __builtin_amdgcn_mfma_f32_16x16x32_bf16(af, bf[0][s], acc[i][0], 0, 0, 0);
                acc[i][1] = __builtin_amdgcn_mfma_f32_16x16x32_bf16(af, bf[1][s], acc[i][1], 0, 0, 0);
            }
        }
    }

    #pragma unroll
    for (int i = 0; i < 6; ++i) {
        #pragma unroll
        for (int rr = 0; rr < 4; ++rr) {
            const int m = i * 16 + lq * 4 + rr;
            const size_t wr = (size_t)(b * Nn + m);
            const ushort4 w40 = *(const ushort4*)(wtp + (wr * Dd + dj0) * 4);
            const ushort4 w41 = *(const ushort4*)(wtp + (wr * Dd + dj1) * 4);
            const float ea0 = silu_f(acc[i][0][rr] + be0);
            const float ea1 = silu_f(acc[i][1][rr] + be1);
            const float sd0 = ws00 * bf2f(w40.x) + ws01 * bf2f(w40.y) + ws02 * bf2f(w40.z);
            const float sd1 = ws10 * bf2f(w41.x) + ws11 * bf2f(w41.y) + ws12 * bf2f(w41.z);
            ipe[((size_t)bn * Nn + m) * Dd + dj0] = ea0 * sd0;
            ipe[((size_t)bn * Nn + m) * Dd + dj1] = ea1 * sd1;
        }
    }
}

extern "C" void kernel_launch(void* const* d_in, const int* in_sizes, int n_in,
                              void* d_out, int out_size, void* d_ws, size_t ws_size,
                              hipStream_t stream)
{
    const float* x    = (const float*)d_in[0];
    const float* vec  = (const float*)d_in[1];
    const float* dist = (const float*)d_in[2];
    const float* edge = (const float*)d_in[3];
    const int*   mask = (const int*)d_in[4];
    const float* Wq   = (const float*)d_in[5];
    const float* bq   = (const float*)d_in[6];
    const float* Wk   = (const float*)d_in[7];
    const float* bk   = (const float*)d_in[8];
    const float* Wv   = (const float*)d_in[9];
    const float* bv   = (const float*)d_in[10];
    const float* Wdk  = (const float*)d_in[11];
    const float* bdk  = (const float*)d_in[12];
    const float* Wdu  = (const float*)d_in[13];
    const float* bdu  = (const float*)d_in[14];
    const float* Wdih = (const float*)d_in[15];
    const float* Wea  = (const float*)d_in[16];
    const float* bea  = (const float*)d_in[17];

    float* out_attn = (float*)d_out;
    float* out_ipe  = out_attn + (size_t)BN * Dd;

    char* wsp = (char*)d_ws;
    unsigned short* ebf  = (unsigned short*)wsp;  wsp += (size_t)MT * Dd * 2;
    float* qb   = (float*)wsp;                    wsp += (size_t)BN * Dd * 4;
    float* kb   = (float*)wsp;                    wsp += (size_t)BN * Dd * 4;
    float* vb   = (float*)wsp;                    wsp += (size_t)BN * Dd * 4;
    float* tb   = (float*)wsp;                    wsp += (size_t)BN * 3 * Dd * 4;
    float* svb  = (float*)wsp;                    wsp += (size_t)BN * 4 * 4;
    float* wsvp = (float*)wsp;                    wsp += (size_t)BN * 3 * Dd * 4;
    unsigned short* wtpp = (unsigned short*)wsp;  wsp += (size_t)BN * Dd * 4 * 2;
    short* Wtdk = (short*)wsp;                    wsp += (size_t)Dd * Dd * 2;
    short* Wtea = (short*)wsp;                    wsp += (size_t)Dd * Dd * 2;

    setup_kernel<<<PREP_BLOCKS + WT_BLOCKS + QKV_BLOCKS, 256, 0, stream>>>(
        edge, ebf, Wdk, Wea, Wtdk, Wtea,
        x, Wq, bq, Wk, bk, Wv, bv, qb, kb, vb);
    dk_attn_kernel<<<BN, 512, 0, stream>>>(ebf, Wtdk, bdk, qb, kb, vb, mask, dist, vec,
                                           out_attn, tb, svb);
    du_kernel<<<BN, 256, 0, stream>>>(tb, svb, Wdu, bdu, Wdih, wsvp, wtpp);
    ea_ipe_kernel<<<BN, 512, 0, stream>>>(ebf, Wtea, bea, wsvp, wtpp, out_ipe);
}